// Round 12
// baseline (193.461 us; speedup 1.0000x reference)
//
#include <hip/hip_runtime.h>
#include <hip/hip_bf16.h>
#include <stdint.h>

typedef __attribute__((ext_vector_type(8))) short short8;
typedef __attribute__((ext_vector_type(4))) float f32x4;
typedef __attribute__((ext_vector_type(4))) unsigned short ushort4v;

#define MFMA_BF16(a,b,c) __builtin_amdgcn_mfma_f32_16x16x32_bf16((a),(b),(c),0,0,0)

static __device__ __forceinline__ unsigned short f2bf(float f){
  union { float fv; unsigned int u; } c; c.fv = f;
  unsigned int u = c.u;
  return (unsigned short)((u + 0x7fffu + ((u >> 16) & 1u)) >> 16);
}

static __device__ __forceinline__ unsigned int cvtpk(float a, float b){
  unsigned int r;
  asm("v_cvt_pk_bf16_f32 %0, %1, %2" : "=v"(r) : "v"(a), "v"(b));
  return r;
}

static __device__ __forceinline__ void gload_lds16(const void* g, void* l){
  __builtin_amdgcn_global_load_lds(
      (const __attribute__((address_space(1))) void*)g,
      (__attribute__((address_space(3))) void*)l, 16, 0, 0);
}

static __device__ __forceinline__ float wred_sum(float v){
  #pragma unroll
  for (int m = 32; m; m >>= 1) v += __shfl_xor(v, m, 64);
  return v;
}

// ---------------- conversion kernels ----------------
__global__ __launch_bounds__(256) void cvt_x_kernel(const float* __restrict__ x,
                                                    unsigned short* __restrict__ o){
  int i = blockIdx.x * 256 + threadIdx.x;
  float4 f = ((const float4*)x)[i];
  ushort4v r;
  r[0] = f2bf(f.x); r[1] = f2bf(f.y); r[2] = f2bf(f.z); r[3] = f2bf(f.w);
  ((ushort4v*)o)[i] = r;
}

__global__ __launch_bounds__(256) void cvt_w_kernel(const float* __restrict__ Wq,
                                                    const float* __restrict__ Wk,
                                                    const float* __restrict__ Wv,
                                                    const float* __restrict__ Ws,
                                                    unsigned short* __restrict__ B){
  int i = blockIdx.x * 256 + threadIdx.x;
  int which = i >> 18;
  const float* src = (which == 0) ? Wq : (which == 1) ? Wk : (which == 2) ? Wv : Ws;
  float4 f = ((const float4*)src)[i & 262143];
  ushort4v r;
  r[0] = f2bf(f.x); r[1] = f2bf(f.y); r[2] = f2bf(f.z); r[3] = f2bf(f.w);
  ((ushort4v*)B)[i] = r;
}

__global__ void wb_prep_kernel(const float* __restrict__ Wb,
                               float* __restrict__ wba, float* __restrict__ wbb){
  int e = blockIdx.x * 256 + threadIdx.x;
  if (e < 1024){
    wba[e] = Wb[e]        + Wb[2048 + e];
    wbb[e] = Wb[1024 + e] - Wb[2048 + e];
  }
}

// masks -> bit planes via ballot
__global__ __launch_bounds__(256) void mask_prep_kernel(
    const int* __restrict__ m, const int* __restrict__ wm,
    unsigned long long* __restrict__ mb, unsigned long long* __restrict__ wb)
{
  const size_t i = (size_t)blockIdx.x * 256 + threadIdx.x;
  const int a = m[i];
  const int c = wm[i];
  unsigned long long ba = __ballot(a != 0);
  unsigned long long bc = __ballot(c != 0);
  if ((threadIdx.x & 63) == 0){
    mb[i >> 6] = ba;
    wb[i >> 6] = bc;
  }
}

// ---------------- fused projection GEMM (pipelined, phase-split) ----------------
// 256x128 tile, 8 waves (4M x 2N), BK=64, 3 LDS bufs, lookahead-2, counted vmcnt(6).
// Each iter = 2 phases: {8 ds_read frags || 3 stage loads -> lgkmcnt(0) -> 16 MFMA}.
// mt-fastest per-XCD ordering: B nt-slice (0.26MB) + A slice (2MB) stay L2-resident.
__global__ __launch_bounds__(512, 1) void gemm_proj_kernel(
    const unsigned short* __restrict__ X, const unsigned short* __restrict__ B,
    unsigned short* __restrict__ qb, unsigned short* __restrict__ kb,
    unsigned short* __restrict__ vT, unsigned short* __restrict__ rbb)
{
  __shared__ __align__(16) unsigned short smem[73728];   // 3 x 24KB tiles
  const int tid = threadIdx.x;
  const int w = tid >> 6, l = tid & 63;
  const int lr = l & 15, lq = l >> 4;
  const int wm = w >> 1, wn = w & 1;
  const int xcd = blockIdx.x & 7, o = blockIdx.x >> 3;           // o in [0,128)
  const int mt = xcd * 4 + (o & 3), nt = o >> 2;                 // mt-fastest in XCD
  const int m0 = mt * 256, n0 = nt * 128;
  const int lrow8 = l >> 3, lc = l & 7;

  f32x4 acc[4][4] = {};

  #define STAGE_H(T, H) { \
    const int bufo_ = ((T) % 3) * 24576; \
    const int kk_ = (T) * 64; \
    _Pragma("unroll") \
    for (int j = (H) * 2; j < (H) * 2 + 2; j++){ \
      const int seg = w + j * 8; \
      const int r = seg * 8 + lrow8; \
      gload_lds16(X + (size_t)(m0 + r) * 1024 + kk_ + ((lc ^ (r & 7)) * 8), \
                  smem + bufo_ + seg * 512); \
    } \
    { \
      const int seg = w + (H) * 8; \
      const int r = seg * 8 + lrow8; \
      gload_lds16(B + (size_t)(n0 + r) * 1024 + kk_ + ((lc ^ (r & 7)) * 8), \
                  smem + bufo_ + 16384 + seg * 512); \
    } }

  #define PHASE(T, SUBK, DOSTAGE) { \
    const int bo_ = ((T) % 3) * 24576; \
    short8 av[4], bv[4]; \
    const int pc = ((((SUBK) * 4 + lq) ^ (lr & 7)) * 8); \
    _Pragma("unroll") \
    for (int mf = 0; mf < 4; mf++) \
      av[mf] = *(const short8*)(smem + bo_ + (wm * 64 + mf * 16 + lr) * 64 + pc); \
    _Pragma("unroll") \
    for (int nf = 0; nf < 4; nf++) \
      bv[nf] = *(const short8*)(smem + bo_ + 16384 + (wn * 64 + nf * 16 + lr) * 64 + pc); \
    if (DOSTAGE) STAGE_H((T) + 2, SUBK) \
    asm volatile("s_waitcnt lgkmcnt(0)" ::: "memory"); \
    __builtin_amdgcn_sched_barrier(0); \
    __builtin_amdgcn_s_setprio(1); \
    _Pragma("unroll") \
    for (int mf = 0; mf < 4; mf++) \
      _Pragma("unroll") \
      for (int nf = 0; nf < 4; nf++) \
        acc[mf][nf] = MFMA_BF16(av[mf], bv[nf], acc[mf][nf]); \
    __builtin_amdgcn_s_setprio(0); }

  STAGE_H(0, 0) STAGE_H(0, 1)
  STAGE_H(1, 0) STAGE_H(1, 1)

  for (int t = 0; t < 15; t++){
    asm volatile("s_waitcnt vmcnt(6)" ::: "memory");
    __builtin_amdgcn_s_barrier();
    const bool st = (t < 14);
    PHASE(t, 0, st)
    __builtin_amdgcn_s_barrier();
    PHASE(t, 1, st)
  }
  asm volatile("s_waitcnt vmcnt(0)" ::: "memory");
  __builtin_amdgcn_s_barrier();
  PHASE(15, 0, false)
  PHASE(15, 1, false)

  // ---- epilogue: LDS-staged coalesced stores ----
  const int which = nt >> 3;
  const int o0 = (nt & 7) * 128;
  if (which == 2){
    __syncthreads();
    #pragma unroll
    for (int mf = 0; mf < 4; mf++)
      #pragma unroll
      for (int nf = 0; nf < 4; nf++){
        const int c = wn * 64 + nf * 16 + lr;
        const int r0v = wm * 64 + mf * 16 + lq * 4;
        uint2 pk;
        pk.x = cvtpk(acc[mf][nf][0], acc[mf][nf][1]);
        pk.y = cvtpk(acc[mf][nf][2], acc[mf][nf][3]);
        *(uint2*)(smem + c * 264 + r0v) = pk;
      }
    __syncthreads();
    #pragma unroll
    for (int p = 0; p < 8; p++){
      const int cid = p * 512 + tid;
      const int c = cid >> 5, bb = (cid >> 1) & 15, sh = cid & 1;
      short8 st;
      #pragma unroll
      for (int j = 0; j < 8; j++) st[j] = (short)smem[c * 264 + (sh * 8 + j) * 16 + bb];
      const int oo = o0 + c;
      const int bh = bb * 16 + (oo >> 6), d = oo & 63;
      *(short8*)(vT + ((size_t)bh * 64 + d) * 512 + mt * 16 + sh * 8) = st;
    }
  } else {
    #pragma unroll
    for (int h2 = 0; h2 < 2; h2++){
      __syncthreads();
      if ((wm >> 1) == h2){
        #pragma unroll
        for (int mf = 0; mf < 4; mf++)
          #pragma unroll
          for (int nf = 0; nf < 4; nf++)
            #pragma unroll
            for (int rg = 0; rg < 4; rg++)
              smem[((wm & 1) * 64 + mf * 16 + lq * 4 + rg) * 136 + wn * 64 + nf * 16 + lr]
                  = f2bf(acc[mf][nf][rg]);
      }
      __syncthreads();
      if (which == 3){
        #pragma unroll
        for (int p = 0; p < 4; p++){
          const int cid = p * 512 + tid;
          const int lrow = cid >> 4, cg = cid & 15;
          short8 vv = *(const short8*)(smem + lrow * 136 + cg * 8);
          *(short8*)(rbb + (size_t)(m0 + h2 * 128 + lrow) * 1024 + o0 + cg * 8) = vv;
        }
      } else {
        unsigned short* dst = (which == 0) ? qb : kb;
        #pragma unroll
        for (int p = 0; p < 4; p++){
          const int cid = p * 512 + tid;
          const int lrow = cid >> 4, cg = cid & 15;
          short8 vv = *(const short8*)(smem + lrow * 136 + cg * 8);
          const int rowi = m0 + h2 * 128 + lrow;
          const int s = rowi >> 4, bb = rowi & 15;
          const int oo = o0 + cg * 8;
          const int bh = bb * 16 + (oo >> 6), d = oo & 63;
          *(short8*)(dst + ((size_t)bh * 512 + s) * 64 + d) = vv;
        }
      }
    }
  }
  #undef STAGE_H
  #undef PHASE
}

// ---------------- fused attention (register-resident softmax) ----------------
// 32 q-rows/block, 4 waves, 4096 blocks; bf16 out. Wave w owns cols
// {c*256 + w*64 + [0,64)} for c=0,1. Scores stay in regs through both softmaxes;
// only final e2 goes to LDS for the PV redistribution.
__global__ __launch_bounds__(256, 3) void attn_kernel(
    const unsigned short* __restrict__ qg, const unsigned short* __restrict__ kg,
    const unsigned short* __restrict__ vt,
    const unsigned char* __restrict__ mbits, const unsigned char* __restrict__ wbits,
    unsigned short* __restrict__ outp)
{
  __shared__ __align__(16) unsigned short sE[32 * 520];
  __shared__ float zbuf1[128];    // [row][wave]
  __shared__ float zbuf2[128];
  const int bid = ((blockIdx.x & 7) << 9) | (blockIdx.x >> 3);  // XCD swizzle
  const int qt = bid & 15, h = (bid >> 4) & 15, b = bid >> 8;   // qt-fastest: K/V L2 reuse
  const int tid = threadIdx.x, w = tid >> 6, l = tid & 63;
  const int lr = l & 15, lq = l >> 4;
  const int bh = b * 16 + h;
  const unsigned short* qp = qg + ((size_t)bh * 512 + qt * 32) * 64;
  const unsigned short* kp = kg + (size_t)bh * 512 * 64;
  const unsigned short* vp = vt + (size_t)bh * 64 * 512;

  // mask u64 per (chunk, row); pre-shift by lr so bit kf*16 is the col bit
  const unsigned char* mbase = mbits + ((size_t)(b * 512 + qt * 32)) * 64;
  const unsigned char* wbase = wbits + ((size_t)(b * 512 + qt * 32)) * 64;
  unsigned long long mus[2][2][4];
  #pragma unroll
  for (int c = 0; c < 2; c++)
    #pragma unroll
    for (int t = 0; t < 2; t++)
      #pragma unroll
      for (int rg = 0; rg < 4; rg++)
        mus[c][t][rg] = (*(const unsigned long long*)(mbase
            + (size_t)(t * 16 + lq * 4 + rg) * 64 + (c * 4 + w) * 8)) >> lr;

  // ---- Phase A: QK^T, e1*mask into regs, z1 partials ----
  short8 qa[2][2];
  #pragma unroll
  for (int t = 0; t < 2; t++){
    qa[t][0] = *(const short8*)(qp + (t * 16 + lr) * 64 + lq * 8);
    qa[t][1] = *(const short8*)(qp + (t * 16 + lr) * 64 + 32 + lq * 8);
  }
  const float CEXP = 0.18033688011112042f;   // 0.125 * log2(e)
  f32x4 em[2][2][4];
  f32x4 z1p[2] = {};
  #pragma unroll
  for (int c = 0; c < 2; c++){
    #pragma unroll
    for (int kf = 0; kf < 4; kf++){
      const unsigned short* kr = kp + (size_t)(c * 256 + w * 64 + kf * 16 + lr) * 64;
      short8 k0 = *(const short8*)(kr + lq * 8);
      short8 k1 = *(const short8*)(kr + 32 + lq * 8);
      f32x4 a0 = {}, a1 = {};
      a0 = MFMA_BF16(qa[0][0], k0, a0);
      a1 = MFMA_BF16(qa[1][0], k0, a1);
      a0 = MFMA_BF16(qa[0][1], k1, a0);
      a1 = MFMA_BF16(qa[1][1], k1, a1);
      #pragma unroll
      for (int t = 0; t < 2; t++){
        f32x4 a = t ? a1 : a0;
        #pragma unroll
        for (int rg = 0; rg < 4; rg++){
          float e = __builtin_amdgcn_exp2f(a[rg] * CEXP);
          const unsigned int bit = (unsigned int)(mus[c][t][rg] >> (kf * 16)) & 1u;
          float v = bit ? e : 0.f;
          em[c][t][kf][rg] = v;
          z1p[t][rg] += v;
        }
      }
    }
  }
  // lr-reduce (cols within 16-lane group) then cross-wave combine
  #pragma unroll
  for (int mm = 1; mm <= 8; mm <<= 1)
    #pragma unroll
    for (int t = 0; t < 2; t++)
      #pragma unroll
      for (int rg = 0; rg < 4; rg++)
        z1p[t][rg] += __shfl_xor(z1p[t][rg], mm, 64);
  if (lr == 0){
    #pragma unroll
    for (int t = 0; t < 2; t++)
      #pragma unroll
      for (int rg = 0; rg < 4; rg++)
        zbuf1[(t * 16 + lq * 4 + rg) * 4 + w] = z1p[t][rg];
  }
  // wmask u64 loads overlap the reduction/barrier
  unsigned long long wus[2][2][4];
  #pragma unroll
  for (int c = 0; c < 2; c++)
    #pragma unroll
    for (int t = 0; t < 2; t++)
      #pragma unroll
      for (int rg = 0; rg < 4; rg++)
        wus[c][t][rg] = (*(const unsigned long long*)(wbase
            + (size_t)(t * 16 + lq * 4 + rg) * 64 + (c * 4 + w) * 8)) >> lr;
  __syncthreads();

  f32x4 il[2];
  #pragma unroll
  for (int t = 0; t < 2; t++)
    #pragma unroll
    for (int rg = 0; rg < 4; rg++){
      float4 zz = *(const float4*)&zbuf1[(t * 16 + lq * 4 + rg) * 4];
      il[t][rg] = 1.4426950408889634f / (zz.x + zz.y + zz.z + zz.w);
    }

  // ---- e2 = exp2(em * i1L) * wmask, in place; z2 partials ----
  f32x4 z2p[2] = {};
  #pragma unroll
  for (int c = 0; c < 2; c++)
    #pragma unroll
    for (int kf = 0; kf < 4; kf++)
      #pragma unroll
      for (int t = 0; t < 2; t++)
        #pragma unroll
        for (int rg = 0; rg < 4; rg++){
          float v = __builtin_amdgcn_exp2f(em[c][t][kf][rg] * il[t][rg]);
          const unsigned int bit = (unsigned int)(wus[c][t][rg] >> (kf * 16)) & 1u;
          float v2 = bit ? v : 0.f;
          em[c][t][kf][rg] = v2;
          z2p[t][rg] += v2;
        }
  #pragma unroll
  for (int mm = 1; mm <= 8; mm <<= 1)
    #pragma unroll
    for (int t = 0; t < 2; t++)
      #pragma unroll
      for (int rg = 0; rg < 4; rg++)
        z2p[t][rg] += __shfl_xor(z2p[t][rg], mm, 64);
  if (lr == 0){
    #pragma unroll
    for (int t = 0; t < 2; t++)
      #pragma unroll
      for (int rg = 0; rg < 4; rg++)
        zbuf2[(t * 16 + lq * 4 + rg) * 4 + w] = z2p[t][rg];
  }
  // store e2 to sE (bf16) for PV redistribution
  #pragma unroll
  for (int c = 0; c < 2; c++)
    #pragma unroll
    for (int kf = 0; kf < 4; kf++)
      #pragma unroll
      for (int t = 0; t < 2; t++){
        unsigned int p01 = cvtpk(em[c][t][kf][0], em[c][t][kf][1]);
        unsigned int p23 = cvtpk(em[c][t][kf][2], em[c][t][kf][3]);
        const int row = t * 16 + lq * 4;
        const int col = c * 256 + w * 64 + kf * 16 + lr;
        sE[(row    ) * 520 + col] = (unsigned short)(p01 & 0xFFFFu);
        sE[(row + 1) * 520 + col] = (unsigned short)(p01 >> 16);
        sE[(row + 2) * 520 + col] = (unsigned short)(p23 & 0xFFFFu);
        sE[(row + 3) * 520 + col] = (unsigned short)(p23 >> 16);
      }
  __syncthreads();

  f32x4 fin[2];
  #pragma unroll
  for (int t = 0; t < 2; t++)
    #pragma unroll
    for (int rg = 0; rg < 4; rg++){
      float4 zz = *(const float4*)&zbuf2[(t * 16 + lq * 4 + rg) * 4];
      fin[t][rg] = 1.f / (zz.x + zz.y + zz.z + zz.w + 1e-10f);
    }

  // ---- Phase C: 2 po chains sharing each V frag; d-frag [16w,16w+16) ----
  {
    f32x4 po0 = {}, po1 = {};
    #pragma unroll
    for (int ks = 0; ks < 16; ks++){
      short8 vf = *(const short8*)(vp + (size_t)(w * 16 + lr) * 512 + ks * 32 + lq * 8);
      short8 af0 = *(const short8*)(sE + (     lr) * 520 + ks * 32 + lq * 8);
      short8 af1 = *(const short8*)(sE + (16 + lr) * 520 + ks * 32 + lq * 8);
      po0 = MFMA_BF16(af0, vf, po0);
      po1 = MFMA_BF16(af1, vf, po1);
    }
    #pragma unroll
    for (int rg = 0; rg < 4; rg++){
      const int r0 = lq * 4 + rg;
      outp[((size_t)(qt * 32 + r0) * 16 + b) * 1024 + h * 64 + w * 16 + lr]
          = f2bf(po0[rg] * fin[0][rg]);
      outp[((size_t)(qt * 32 + 16 + r0) * 16 + b) * 1024 + h * 64 + w * 16 + lr]
          = f2bf(po1[rg] * fin[1][rg]);
    }
  }
}

// ---------------- gate + mix ----------------
__global__ __launch_bounds__(256) void gate_kernel(
    const unsigned short* __restrict__ outp, const unsigned short* __restrict__ rbb,
    const float* __restrict__ wba, const float* __restrict__ wbb,
    float* __restrict__ y)
{
  const int t = blockIdx.x * 4 + (threadIdx.x >> 6);
  const int l = threadIdx.x & 63;
  const unsigned short* o = outp + (size_t)t * 1024;
  const unsigned short* r = rbb + (size_t)t * 1024;
  float ov[16], rv[16];
  float acc = 0.f;
  #pragma unroll
  for (int j = 0; j < 16; j++){
    const int e = j * 64 + l;
    ov[j] = __uint_as_float((unsigned int)o[e] << 16);
    rv[j] = __uint_as_float((unsigned int)r[e] << 16);
    acc += ov[j] * wba[e] + rv[j] * wbb[e];
  }
  const float dot = wred_sum(acc);
  const float g = 1.f / (1.f + __builtin_amdgcn_exp2f(-dot * 1.4426950408889634f));
  float* yo = y + (size_t)t * 1024;
  #pragma unroll
  for (int j = 0; j < 16; j++){
    const int e = j * 64 + l;
    yo[e] = g * rv[j] + (1.f - g) * ov[j];
  }
}

// ---------------- launch ----------------
extern "C" void kernel_launch(void* const* d_in, const int* in_sizes, int n_in,
                              void* d_out, int out_size, void* d_ws, size_t ws_size,
                              hipStream_t stream)
{
  (void)in_sizes; (void)n_in; (void)out_size; (void)ws_size;
  const float* x   = (const float*)d_in[0];
  const int* mask  = (const int*)d_in[1];
  const int* wmask = (const int*)d_in[2];
  const float* Wq  = (const float*)d_in[3];
  const float* Wk  = (const float*)d_in[4];
  const float* Wv  = (const float*)d_in[5];
  const float* Ws  = (const float*)d_in[6];
  const float* Wb  = (const float*)d_in[7];

  char* ws = (char*)d_ws;
  unsigned short* xbf = (unsigned short*)ws; ws += 16777216;
  unsigned short* bm  = (unsigned short*)ws; ws += 8388608;
  unsigned short* qb  = (unsigned short*)ws; ws += 16777216;
  unsigned short* kb  = (unsigned short*)ws; ws += 16777216;
  unsigned short* vT  = (unsigned short*)ws; ws += 16777216;
  unsigned short* rbb = (unsigned short*)ws; ws += 16777216;
  unsigned short* op  = (unsigned short*)ws; ws += 16777216;
  float* wba = (float*)ws; ws += 4096;
  float* wbb = (float*)ws; ws += 4096;
  unsigned long long* mb64 = (unsigned long long*)xbf;
  unsigned long long* wb64 = (unsigned long long*)bm;

  cvt_x_kernel<<<8192, 256, 0, stream>>>(x, xbf);
  cvt_w_kernel<<<4096, 256, 0, stream>>>(Wq, Wk, Wv, Ws, bm);
  wb_prep_kernel<<<4, 256, 0, stream>>>(Wb, wba, wbb);
  gemm_proj_kernel<<<1024, 512, 0, stream>>>(xbf, bm, qb, kb, vT, rbb);
  mask_prep_kernel<<<16384, 256, 0, stream>>>(mask, wmask, mb64, wb64);
  attn_kernel<<<4096, 256, 0, stream>>>(qb, kb, vT,
      (const unsigned char*)mb64, (const unsigned char*)wb64, op);
  gate_kernel<<<2048, 256, 0, stream>>>(op, rbb, wba, wbb, (float*)d_out);
}

// Round 13
// 181.985 us; speedup vs baseline: 1.0631x; 1.0631x over previous
//
#include <hip/hip_runtime.h>
#include <hip/hip_bf16.h>
#include <stdint.h>

typedef __attribute__((ext_vector_type(8))) short short8;
typedef __attribute__((ext_vector_type(4))) float f32x4;
typedef __attribute__((ext_vector_type(4))) unsigned short ushort4v;

#define MFMA_BF16(a,b,c) __builtin_amdgcn_mfma_f32_16x16x32_bf16((a),(b),(c),0,0,0)

static __device__ __forceinline__ unsigned short f2bf(float f){
  union { float fv; unsigned int u; } c; c.fv = f;
  unsigned int u = c.u;
  return (unsigned short)((u + 0x7fffu + ((u >> 16) & 1u)) >> 16);
}

static __device__ __forceinline__ unsigned int cvtpk(float a, float b){
  unsigned int r;
  asm("v_cvt_pk_bf16_f32 %0, %1, %2" : "=v"(r) : "v"(a), "v"(b));
  return r;
}

static __device__ __forceinline__ void gload_lds16(const void* g, void* l){
  __builtin_amdgcn_global_load_lds(
      (const __attribute__((address_space(1))) void*)g,
      (__attribute__((address_space(3))) void*)l, 16, 0, 0);
}

static __device__ __forceinline__ float wred_sum(float v){
  #pragma unroll
  for (int m = 32; m; m >>= 1) v += __shfl_xor(v, m, 64);
  return v;
}

static __device__ __forceinline__ void unpack8(uint4 u, float* f){
  f[0] = __uint_as_float(u.x << 16); f[1] = __uint_as_float(u.x & 0xFFFF0000u);
  f[2] = __uint_as_float(u.y << 16); f[3] = __uint_as_float(u.y & 0xFFFF0000u);
  f[4] = __uint_as_float(u.z << 16); f[5] = __uint_as_float(u.z & 0xFFFF0000u);
  f[6] = __uint_as_float(u.w << 16); f[7] = __uint_as_float(u.w & 0xFFFF0000u);
}

// ---------------- conversion kernels ----------------
__global__ __launch_bounds__(256) void cvt_x_kernel(const float* __restrict__ x,
                                                    unsigned short* __restrict__ o){
  int i = blockIdx.x * 256 + threadIdx.x;
  float4 f = ((const float4*)x)[i];
  ushort4v r;
  r[0] = f2bf(f.x); r[1] = f2bf(f.y); r[2] = f2bf(f.z); r[3] = f2bf(f.w);
  ((ushort4v*)o)[i] = r;
}

__global__ __launch_bounds__(256) void cvt_w_kernel(const float* __restrict__ Wq,
                                                    const float* __restrict__ Wk,
                                                    const float* __restrict__ Wv,
                                                    const float* __restrict__ Ws,
                                                    unsigned short* __restrict__ B){
  int i = blockIdx.x * 256 + threadIdx.x;
  int which = i >> 18;
  const float* src = (which == 0) ? Wq : (which == 1) ? Wk : (which == 2) ? Wv : Ws;
  float4 f = ((const float4*)src)[i & 262143];
  ushort4v r;
  r[0] = f2bf(f.x); r[1] = f2bf(f.y); r[2] = f2bf(f.z); r[3] = f2bf(f.w);
  ((ushort4v*)B)[i] = r;
}

__global__ void wb_prep_kernel(const float* __restrict__ Wb,
                               float* __restrict__ wba, float* __restrict__ wbb){
  int e = blockIdx.x * 256 + threadIdx.x;
  if (e < 1024){
    wba[e] = Wb[e]        + Wb[2048 + e];
    wbb[e] = Wb[1024 + e] - Wb[2048 + e];
  }
}

// masks -> bit planes via ballot
__global__ __launch_bounds__(256) void mask_prep_kernel(
    const int* __restrict__ m, const int* __restrict__ wm,
    unsigned long long* __restrict__ mb, unsigned long long* __restrict__ wb)
{
  const size_t i = (size_t)blockIdx.x * 256 + threadIdx.x;
  const int a = m[i];
  const int c = wm[i];
  unsigned long long ba = __ballot(a != 0);
  unsigned long long bc = __ballot(c != 0);
  if ((threadIdx.x & 63) == 0){
    mb[i >> 6] = ba;
    wb[i >> 6] = bc;
  }
}

// ---------------- fused projection GEMM (pipelined, phase-split) ----------------
__global__ __launch_bounds__(512, 1) void gemm_proj_kernel(
    const unsigned short* __restrict__ X, const unsigned short* __restrict__ B,
    unsigned short* __restrict__ qb, unsigned short* __restrict__ kb,
    unsigned short* __restrict__ vT, unsigned short* __restrict__ rbb)
{
  __shared__ __align__(16) unsigned short smem[73728];   // 3 x 24KB tiles
  const int tid = threadIdx.x;
  const int w = tid >> 6, l = tid & 63;
  const int lr = l & 15, lq = l >> 4;
  const int wm = w >> 1, wn = w & 1;
  const int xcd = blockIdx.x & 7, o = blockIdx.x >> 3;           // o in [0,128)
  const int mt = xcd * 4 + (o & 3), nt = o >> 2;                 // mt-fastest in XCD
  const int m0 = mt * 256, n0 = nt * 128;
  const int lrow8 = l >> 3, lc = l & 7;

  f32x4 acc[4][4] = {};

  #define STAGE_H(T, H) { \
    const int bufo_ = ((T) % 3) * 24576; \
    const int kk_ = (T) * 64; \
    _Pragma("unroll") \
    for (int j = (H) * 2; j < (H) * 2 + 2; j++){ \
      const int seg = w + j * 8; \
      const int r = seg * 8 + lrow8; \
      gload_lds16(X + (size_t)(m0 + r) * 1024 + kk_ + ((lc ^ (r & 7)) * 8), \
                  smem + bufo_ + seg * 512); \
    } \
    { \
      const int seg = w + (H) * 8; \
      const int r = seg * 8 + lrow8; \
      gload_lds16(B + (size_t)(n0 + r) * 1024 + kk_ + ((lc ^ (r & 7)) * 8), \
                  smem + bufo_ + 16384 + seg * 512); \
    } }

  #define PHASE(T, SUBK, DOSTAGE) { \
    const int bo_ = ((T) % 3) * 24576; \
    short8 av[4], bv[4]; \
    const int pc = ((((SUBK) * 4 + lq) ^ (lr & 7)) * 8); \
    _Pragma("unroll") \
    for (int mf = 0; mf < 4; mf++) \
      av[mf] = *(const short8*)(smem + bo_ + (wm * 64 + mf * 16 + lr) * 64 + pc); \
    _Pragma("unroll") \
    for (int nf = 0; nf < 4; nf++) \
      bv[nf] = *(const short8*)(smem + bo_ + 16384 + (wn * 64 + nf * 16 + lr) * 64 + pc); \
    if (DOSTAGE) STAGE_H((T) + 2, SUBK) \
    asm volatile("s_waitcnt lgkmcnt(0)" ::: "memory"); \
    __builtin_amdgcn_sched_barrier(0); \
    __builtin_amdgcn_s_setprio(1); \
    _Pragma("unroll") \
    for (int mf = 0; mf < 4; mf++) \
      _Pragma("unroll") \
      for (int nf = 0; nf < 4; nf++) \
        acc[mf][nf] = MFMA_BF16(av[mf], bv[nf], acc[mf][nf]); \
    __builtin_amdgcn_s_setprio(0); }

  STAGE_H(0, 0) STAGE_H(0, 1)
  STAGE_H(1, 0) STAGE_H(1, 1)

  for (int t = 0; t < 15; t++){
    asm volatile("s_waitcnt vmcnt(6)" ::: "memory");
    __builtin_amdgcn_s_barrier();
    const bool st = (t < 14);
    PHASE(t, 0, st)
    __builtin_amdgcn_s_barrier();
    PHASE(t, 1, st)
  }
  asm volatile("s_waitcnt vmcnt(0)" ::: "memory");
  __builtin_amdgcn_s_barrier();
  PHASE(15, 0, false)
  PHASE(15, 1, false)

  // ---- epilogue: LDS-staged coalesced stores ----
  const int which = nt >> 3;
  const int o0 = (nt & 7) * 128;
  if (which == 2){
    __syncthreads();
    #pragma unroll
    for (int mf = 0; mf < 4; mf++)
      #pragma unroll
      for (int nf = 0; nf < 4; nf++){
        const int c = wn * 64 + nf * 16 + lr;
        const int r0v = wm * 64 + mf * 16 + lq * 4;
        uint2 pk;
        pk.x = cvtpk(acc[mf][nf][0], acc[mf][nf][1]);
        pk.y = cvtpk(acc[mf][nf][2], acc[mf][nf][3]);
        *(uint2*)(smem + c * 264 + r0v) = pk;
      }
    __syncthreads();
    #pragma unroll
    for (int p = 0; p < 8; p++){
      const int cid = p * 512 + tid;
      const int c = cid >> 5, bb = (cid >> 1) & 15, sh = cid & 1;
      short8 st;
      #pragma unroll
      for (int j = 0; j < 8; j++) st[j] = (short)smem[c * 264 + (sh * 8 + j) * 16 + bb];
      const int oo = o0 + c;
      const int bh = bb * 16 + (oo >> 6), d = oo & 63;
      *(short8*)(vT + ((size_t)bh * 64 + d) * 512 + mt * 16 + sh * 8) = st;
    }
  } else {
    #pragma unroll
    for (int h2 = 0; h2 < 2; h2++){
      __syncthreads();
      if ((wm >> 1) == h2){
        #pragma unroll
        for (int mf = 0; mf < 4; mf++)
          #pragma unroll
          for (int nf = 0; nf < 4; nf++)
            #pragma unroll
            for (int rg = 0; rg < 4; rg++)
              smem[((wm & 1) * 64 + mf * 16 + lq * 4 + rg) * 136 + wn * 64 + nf * 16 + lr]
                  = f2bf(acc[mf][nf][rg]);
      }
      __syncthreads();
      if (which == 3){
        #pragma unroll
        for (int p = 0; p < 4; p++){
          const int cid = p * 512 + tid;
          const int lrow = cid >> 4, cg = cid & 15;
          short8 vv = *(const short8*)(smem + lrow * 136 + cg * 8);
          *(short8*)(rbb + (size_t)(m0 + h2 * 128 + lrow) * 1024 + o0 + cg * 8) = vv;
        }
      } else {
        unsigned short* dst = (which == 0) ? qb : kb;
        #pragma unroll
        for (int p = 0; p < 4; p++){
          const int cid = p * 512 + tid;
          const int lrow = cid >> 4, cg = cid & 15;
          short8 vv = *(const short8*)(smem + lrow * 136 + cg * 8);
          const int rowi = m0 + h2 * 128 + lrow;
          const int s = rowi >> 4, bb = rowi & 15;
          const int oo = o0 + cg * 8;
          const int bh = bb * 16 + (oo >> 6), d = oo & 63;
          *(short8*)(dst + ((size_t)bh * 512 + s) * 64 + d) = vv;
        }
      }
    }
  }
  #undef STAGE_H
  #undef PHASE
}

// ---------------- fused attention ----------------
// r11 structure + z1 fused into Phase A: store MASKED e1 to LDS, accumulate z1
// partials in regs (shfl over lr + zbuf combine). Phase B starts at e2.
__global__ __launch_bounds__(256, 4) void attn_kernel(
    const unsigned short* __restrict__ qg, const unsigned short* __restrict__ kg,
    const unsigned short* __restrict__ vt,
    const unsigned char* __restrict__ mbits, const unsigned char* __restrict__ wbits,
    unsigned short* __restrict__ outp)
{
  __shared__ __align__(16) unsigned short sE[32 * 520];
  __shared__ float zbuf1[128];    // [row][wave]
  __shared__ float sfin[32];
  const int bid = ((blockIdx.x & 7) << 9) | (blockIdx.x >> 3);  // XCD swizzle
  const int qt = bid & 15, h = (bid >> 4) & 15, b = bid >> 8;   // qt-fastest: K/V L2 reuse
  const int tid = threadIdx.x, w = tid >> 6, l = tid & 63;
  const int lr = l & 15, lq = l >> 4;
  const int bh = b * 16 + h;
  const unsigned short* qp = qg + ((size_t)bh * 512 + qt * 32) * 64;
  const unsigned short* kp = kg + (size_t)bh * 512 * 64;
  const unsigned short* vp = vt + (size_t)bh * 64 * 512;

  const unsigned char* mbase = mbits + ((size_t)(b * 512 + qt * 32)) * 64;
  const unsigned char* wrb   = wbits + ((size_t)(b * 512 + qt * 32)) * 64;

  // Phase-A masks: rows t*16+lq*4+rg, cols w*128 + [0,128): two u64 per row,
  // pre-shifted by lr so bit kf*16 selects col kf*16+lr.
  unsigned long long mus[2][4][2];
  #pragma unroll
  for (int t = 0; t < 2; t++)
    #pragma unroll
    for (int rg = 0; rg < 4; rg++){
      const unsigned char* rp = mbase + (size_t)(t * 16 + lq * 4 + rg) * 64 + w * 16;
      mus[t][rg][0] = (*(const unsigned long long*)(rp    )) >> lr;
      mus[t][rg][1] = (*(const unsigned long long*)(rp + 8)) >> lr;
    }

  // ---- Phase A: QK^T, masked e1 -> LDS, z1 partials in regs ----
  short8 qa[2][2];
  #pragma unroll
  for (int t = 0; t < 2; t++){
    qa[t][0] = *(const short8*)(qp + (t * 16 + lr) * 64 + lq * 8);
    qa[t][1] = *(const short8*)(qp + (t * 16 + lr) * 64 + 32 + lq * 8);
  }
  const float CEXP = 0.18033688011112042f;   // 0.125 * log2(e)
  f32x4 z1p[2] = {};
  #pragma unroll
  for (int kf = 0; kf < 8; kf++){
    const unsigned short* kr = kp + (size_t)(w * 128 + kf * 16 + lr) * 64;
    short8 k0 = *(const short8*)(kr + lq * 8);
    short8 k1 = *(const short8*)(kr + 32 + lq * 8);
    f32x4 a0 = {}, a1 = {};
    a0 = MFMA_BF16(qa[0][0], k0, a0);
    a1 = MFMA_BF16(qa[1][0], k0, a1);
    a0 = MFMA_BF16(qa[0][1], k1, a0);
    a1 = MFMA_BF16(qa[1][1], k1, a1);
    const int col = w * 128 + kf * 16 + lr;
    #pragma unroll
    for (int t = 0; t < 2; t++){
      f32x4 a = t ? a1 : a0;
      float v[4];
      #pragma unroll
      for (int rg = 0; rg < 4; rg++){
        float e = __builtin_amdgcn_exp2f(a[rg] * CEXP);
        const unsigned int bit = (unsigned int)(
            (kf < 4 ? mus[t][rg][0] >> (kf * 16) : mus[t][rg][1] >> ((kf - 4) * 16))) & 1u;
        v[rg] = bit ? e : 0.f;
        z1p[t][rg] += v[rg];
      }
      unsigned int p01 = cvtpk(v[0], v[1]), p23 = cvtpk(v[2], v[3]);
      const int row = t * 16 + lq * 4;
      sE[(row    ) * 520 + col] = (unsigned short)(p01 & 0xFFFFu);
      sE[(row + 1) * 520 + col] = (unsigned short)(p01 >> 16);
      sE[(row + 2) * 520 + col] = (unsigned short)(p23 & 0xFFFFu);
      sE[(row + 3) * 520 + col] = (unsigned short)(p23 >> 16);
    }
  }
  // z1 partial reduce over lr (cols within 16-lane group), then cross-wave slot
  #pragma unroll
  for (int mm = 1; mm <= 8; mm <<= 1)
    #pragma unroll
    for (int t = 0; t < 2; t++)
      #pragma unroll
      for (int rg = 0; rg < 4; rg++)
        z1p[t][rg] += __shfl_xor(z1p[t][rg], mm, 64);
  if (lr == 0){
    #pragma unroll
    for (int t = 0; t < 2; t++)
      #pragma unroll
      for (int rg = 0; rg < 4; rg++)
        zbuf1[(t * 16 + lq * 4 + rg) * 4 + w] = z1p[t][rg];
  }

  // Phase-B wmask bytes (rows g*16 + w*4 + rr), loads overlap the barrier
  unsigned int wby[2][4];
  #pragma unroll
  for (int g = 0; g < 2; g++)
    #pragma unroll
    for (int rr = 0; rr < 4; rr++)
      wby[g][rr] = wrb[(g * 16 + w * 4 + rr) * 64 + l];
  __syncthreads();

  // ---- Phase B: second softmax only (z1 known), 2 groups x 4 rows ----
  #pragma unroll
  for (int g = 0; g < 2; g++){
    const int row0 = g * 16 + w * 4;
    uint4 ev[4];
    float i1L[4];
    #pragma unroll
    for (int rr = 0; rr < 4; rr++){
      ev[rr] = *(const uint4*)(sE + (row0 + rr) * 520 + l * 8);
      float4 zz = *(const float4*)&zbuf1[(row0 + rr) * 4];
      i1L[rr] = 1.4426950408889634f / (zz.x + zz.y + zz.z + zz.w);
    }
    float e2[4][8]; float z2[4];
    #pragma unroll
    for (int rr = 0; rr < 4; rr++){
      float e1m[8];
      unpack8(ev[rr], e1m);
      const unsigned int wv = wby[g][rr];
      float z = 0.f;
      #pragma unroll
      for (int j = 0; j < 8; j++){
        float t = __builtin_amdgcn_exp2f(e1m[j] * i1L[rr]);
        e2[rr][j] = ((wv >> j) & 1u) ? t : 0.f;
        z += e2[rr][j];
      }
      z2[rr] = z;
    }
    #pragma unroll
    for (int mm = 32; mm; mm >>= 1){
      #pragma unroll
      for (int rr = 0; rr < 4; rr++) z2[rr] += __shfl_xor(z2[rr], mm, 64);
    }
    #pragma unroll
    for (int rr = 0; rr < 4; rr++){
      uint4 oo;
      oo.x = cvtpk(e2[rr][0], e2[rr][1]); oo.y = cvtpk(e2[rr][2], e2[rr][3]);
      oo.z = cvtpk(e2[rr][4], e2[rr][5]); oo.w = cvtpk(e2[rr][6], e2[rr][7]);
      *(uint4*)(sE + (row0 + rr) * 520 + l * 8) = oo;
      if (l == 0) sfin[row0 + rr] = 1.f / (z2[rr] + 1e-10f);
    }
  }
  __syncthreads();

  // ---- Phase C: 2 po chains sharing each V frag; d-frag [16w,16w+16) ----
  {
    f32x4 po0 = {}, po1 = {};
    #pragma unroll
    for (int ks = 0; ks < 16; ks++){
      short8 vf = *(const short8*)(vp + (size_t)(w * 16 + lr) * 512 + ks * 32 + lq * 8);
      short8 af0 = *(const short8*)(sE + (     lr) * 520 + ks * 32 + lq * 8);
      short8 af1 = *(const short8*)(sE + (16 + lr) * 520 + ks * 32 + lq * 8);
      po0 = MFMA_BF16(af0, vf, po0);
      po1 = MFMA_BF16(af1, vf, po1);
    }
    #pragma unroll
    for (int rg = 0; rg < 4; rg++){
      const int r0 = lq * 4 + rg;
      outp[((size_t)(qt * 32 + r0) * 16 + b) * 1024 + h * 64 + w * 16 + lr]
          = f2bf(po0[rg] * sfin[r0]);
      outp[((size_t)(qt * 32 + 16 + r0) * 16 + b) * 1024 + h * 64 + w * 16 + lr]
          = f2bf(po1[rg] * sfin[16 + r0]);
    }
  }
}

// ---------------- gate + mix ----------------
__global__ __launch_bounds__(256) void gate_kernel(
    const unsigned short* __restrict__ outp, const unsigned short* __restrict__ rbb,
    const float* __restrict__ wba, const float* __restrict__ wbb,
    float* __restrict__ y)
{
  const int t = blockIdx.x * 4 + (threadIdx.x >> 6);
  const int l = threadIdx.x & 63;
  const unsigned short* o = outp + (size_t)t * 1024;
  const unsigned short* r = rbb + (size_t)t * 1024;
  float ov[16], rv[16];
  float acc = 0.f;
  #pragma unroll
  for (int j = 0; j < 16; j++){
    const int e = j * 64 + l;
    ov[j] = __uint_as_float((unsigned int)o[e] << 16);
    rv[j] = __uint_as_float((unsigned int)r[e] << 16);
    acc += ov[j] * wba[e] + rv[j] * wbb[e];
  }
  const float dot = wred_sum(acc);
  const float g = 1.f / (1.f + __builtin_amdgcn_exp2f(-dot * 1.4426950408889634f));
  float* yo = y + (size_t)t * 1024;
  #pragma unroll
  for (int j = 0; j < 16; j++){
    const int e = j * 64 + l;
    yo[e] = g * rv[j] + (1.f - g) * ov[j];
  }
}

// ---------------- launch ----------------
extern "C" void kernel_launch(void* const* d_in, const int* in_sizes, int n_in,
                              void* d_out, int out_size, void* d_ws, size_t ws_size,
                              hipStream_t stream)
{
  (void)in_sizes; (void)n_in; (void)out_size; (void)ws_size;
  const float* x   = (const float*)d_in[0];
  const int* mask  = (const int*)d_in[1];
  const int* wmask = (const int*)d_in[2];
  const float* Wq  = (const float*)d_in[3];
  const float* Wk  = (const float*)d_in[4];
  const float* Wv  = (const float*)d_in[5];
  const float* Ws  = (const float*)d_in[6];
  const float* Wb  = (const float*)d_in[7];

  char* ws = (char*)d_ws;
  unsigned short* xbf = (unsigned short*)ws; ws += 16777216;
  unsigned short* bm  = (unsigned short*)ws; ws += 8388608;
  unsigned short* qb  = (unsigned short*)ws; ws += 16777216;
  unsigned short* kb  = (unsigned short*)ws; ws += 16777216;
  unsigned short* vT  = (unsigned short*)ws; ws += 16777216;
  unsigned short* rbb = (unsigned short*)ws; ws += 16777216;
  unsigned short* op  = (unsigned short*)ws; ws += 16777216;
  float* wba = (float*)ws; ws += 4096;
  float* wbb = (float*)ws; ws += 4096;
  unsigned long long* mb64 = (unsigned long long*)xbf;
  unsigned long long* wb64 = (unsigned long long*)bm;

  cvt_x_kernel<<<8192, 256, 0, stream>>>(x, xbf);
  cvt_w_kernel<<<4096, 256, 0, stream>>>(Wq, Wk, Wv, Ws, bm);
  wb_prep_kernel<<<4, 256, 0, stream>>>(Wb, wba, wbb);
  gemm_proj_kernel<<<1024, 512, 0, stream>>>(xbf, bm, qb, kb, vT, rbb);
  mask_prep_kernel<<<16384, 256, 0, stream>>>(mask, wmask, mb64, wb64);
  attn_kernel<<<4096, 256, 0, stream>>>(qb, kb, vT,
      (const unsigned char*)mb64, (const unsigned char*)wb64, op);
  gate_kernel<<<2048, 256, 0, stream>>>(op, rbb, wba, wbb, (float*)d_out);
}

// Round 14
// 178.909 us; speedup vs baseline: 1.0813x; 1.0172x over previous
//
#include <hip/hip_runtime.h>
#include <hip/hip_bf16.h>
#include <stdint.h>

typedef __attribute__((ext_vector_type(8))) short short8;
typedef __attribute__((ext_vector_type(4))) float f32x4;
typedef __attribute__((ext_vector_type(4))) unsigned short ushort4v;

#define MFMA_BF16(a,b,c) __builtin_amdgcn_mfma_f32_16x16x32_bf16((a),(b),(c),0,0,0)

static __device__ __forceinline__ unsigned short f2bf(float f){
  union { float fv; unsigned int u; } c; c.fv = f;
  unsigned int u = c.u;
  return (unsigned short)((u + 0x7fffu + ((u >> 16) & 1u)) >> 16);
}

static __device__ __forceinline__ unsigned int cvtpk(float a, float b){
  unsigned int r;
  asm("v_cvt_pk_bf16_f32 %0, %1, %2" : "=v"(r) : "v"(a), "v"(b));
  return r;
}

static __device__ __forceinline__ void gload_lds16(const void* g, void* l){
  __builtin_amdgcn_global_load_lds(
      (const __attribute__((address_space(1))) void*)g,
      (__attribute__((address_space(3))) void*)l, 16, 0, 0);
}

static __device__ __forceinline__ float wred_sum(float v){
  #pragma unroll
  for (int m = 32; m; m >>= 1) v += __shfl_xor(v, m, 64);
  return v;
}

static __device__ __forceinline__ void unpack8(uint4 u, float* f){
  f[0] = __uint_as_float(u.x << 16); f[1] = __uint_as_float(u.x & 0xFFFF0000u);
  f[2] = __uint_as_float(u.y << 16); f[3] = __uint_as_float(u.y & 0xFFFF0000u);
  f[4] = __uint_as_float(u.z << 16); f[5] = __uint_as_float(u.z & 0xFFFF0000u);
  f[6] = __uint_as_float(u.w << 16); f[7] = __uint_as_float(u.w & 0xFFFF0000u);
}

// ---------------- conversion kernels ----------------
__global__ __launch_bounds__(256) void cvt_x_kernel(const float* __restrict__ x,
                                                    unsigned short* __restrict__ o){
  int i = blockIdx.x * 256 + threadIdx.x;
  float4 f = ((const float4*)x)[i];
  ushort4v r;
  r[0] = f2bf(f.x); r[1] = f2bf(f.y); r[2] = f2bf(f.z); r[3] = f2bf(f.w);
  ((ushort4v*)o)[i] = r;
}

__global__ __launch_bounds__(256) void cvt_w_kernel(const float* __restrict__ Wq,
                                                    const float* __restrict__ Wk,
                                                    const float* __restrict__ Wv,
                                                    const float* __restrict__ Ws,
                                                    unsigned short* __restrict__ B){
  int i = blockIdx.x * 256 + threadIdx.x;
  int which = i >> 18;
  const float* src = (which == 0) ? Wq : (which == 1) ? Wk : (which == 2) ? Wv : Ws;
  float4 f = ((const float4*)src)[i & 262143];
  ushort4v r;
  r[0] = f2bf(f.x); r[1] = f2bf(f.y); r[2] = f2bf(f.z); r[3] = f2bf(f.w);
  ((ushort4v*)B)[i] = r;
}

__global__ void wb_prep_kernel(const float* __restrict__ Wb,
                               float* __restrict__ wba, float* __restrict__ wbb){
  int e = blockIdx.x * 256 + threadIdx.x;
  if (e < 1024){
    wba[e] = Wb[e]        + Wb[2048 + e];
    wbb[e] = Wb[1024 + e] - Wb[2048 + e];
  }
}

// masks -> bit planes via ballot
__global__ __launch_bounds__(256) void mask_prep_kernel(
    const int* __restrict__ m, const int* __restrict__ wm,
    unsigned long long* __restrict__ mb, unsigned long long* __restrict__ wb)
{
  const size_t i = (size_t)blockIdx.x * 256 + threadIdx.x;
  const int a = m[i];
  const int c = wm[i];
  unsigned long long ba = __ballot(a != 0);
  unsigned long long bc = __ballot(c != 0);
  if ((threadIdx.x & 63) == 0){
    mb[i >> 6] = ba;
    wb[i >> 6] = bc;
  }
}

// ---------------- fused projection GEMM (pipelined, phase-split) ----------------
__global__ __launch_bounds__(512, 1) void gemm_proj_kernel(
    const unsigned short* __restrict__ X, const unsigned short* __restrict__ B,
    unsigned short* __restrict__ qb, unsigned short* __restrict__ kb,
    unsigned short* __restrict__ vT, unsigned short* __restrict__ rbb)
{
  __shared__ __align__(16) unsigned short smem[73728];   // 3 x 24KB tiles
  const int tid = threadIdx.x;
  const int w = tid >> 6, l = tid & 63;
  const int lr = l & 15, lq = l >> 4;
  const int wm = w >> 1, wn = w & 1;
  const int xcd = blockIdx.x & 7, o = blockIdx.x >> 3;           // o in [0,128)
  const int mt = xcd * 4 + (o & 3), nt = o >> 2;                 // mt-fastest in XCD
  const int m0 = mt * 256, n0 = nt * 128;
  const int lrow8 = l >> 3, lc = l & 7;

  f32x4 acc[4][4] = {};

  #define STAGE_H(T, H) { \
    const int bufo_ = ((T) % 3) * 24576; \
    const int kk_ = (T) * 64; \
    _Pragma("unroll") \
    for (int j = (H) * 2; j < (H) * 2 + 2; j++){ \
      const int seg = w + j * 8; \
      const int r = seg * 8 + lrow8; \
      gload_lds16(X + (size_t)(m0 + r) * 1024 + kk_ + ((lc ^ (r & 7)) * 8), \
                  smem + bufo_ + seg * 512); \
    } \
    { \
      const int seg = w + (H) * 8; \
      const int r = seg * 8 + lrow8; \
      gload_lds16(B + (size_t)(n0 + r) * 1024 + kk_ + ((lc ^ (r & 7)) * 8), \
                  smem + bufo_ + 16384 + seg * 512); \
    } }

  #define PHASE(T, SUBK, DOSTAGE) { \
    const int bo_ = ((T) % 3) * 24576; \
    short8 av[4], bv[4]; \
    const int pc = ((((SUBK) * 4 + lq) ^ (lr & 7)) * 8); \
    _Pragma("unroll") \
    for (int mf = 0; mf < 4; mf++) \
      av[mf] = *(const short8*)(smem + bo_ + (wm * 64 + mf * 16 + lr) * 64 + pc); \
    _Pragma("unroll") \
    for (int nf = 0; nf < 4; nf++) \
      bv[nf] = *(const short8*)(smem + bo_ + 16384 + (wn * 64 + nf * 16 + lr) * 64 + pc); \
    if (DOSTAGE) STAGE_H((T) + 2, SUBK) \
    asm volatile("s_waitcnt lgkmcnt(0)" ::: "memory"); \
    __builtin_amdgcn_sched_barrier(0); \
    __builtin_amdgcn_s_setprio(1); \
    _Pragma("unroll") \
    for (int mf = 0; mf < 4; mf++) \
      _Pragma("unroll") \
      for (int nf = 0; nf < 4; nf++) \
        acc[mf][nf] = MFMA_BF16(av[mf], bv[nf], acc[mf][nf]); \
    __builtin_amdgcn_s_setprio(0); }

  STAGE_H(0, 0) STAGE_H(0, 1)
  STAGE_H(1, 0) STAGE_H(1, 1)

  for (int t = 0; t < 15; t++){
    asm volatile("s_waitcnt vmcnt(6)" ::: "memory");
    __builtin_amdgcn_s_barrier();
    const bool st = (t < 14);
    PHASE(t, 0, st)
    __builtin_amdgcn_s_barrier();
    PHASE(t, 1, st)
  }
  asm volatile("s_waitcnt vmcnt(0)" ::: "memory");
  __builtin_amdgcn_s_barrier();
  PHASE(15, 0, false)
  PHASE(15, 1, false)

  // ---- epilogue: LDS-staged coalesced stores ----
  const int which = nt >> 3;
  const int o0 = (nt & 7) * 128;
  if (which == 2){
    __syncthreads();
    #pragma unroll
    for (int mf = 0; mf < 4; mf++)
      #pragma unroll
      for (int nf = 0; nf < 4; nf++){
        const int c = wn * 64 + nf * 16 + lr;
        const int r0v = wm * 64 + mf * 16 + lq * 4;
        uint2 pk;
        pk.x = cvtpk(acc[mf][nf][0], acc[mf][nf][1]);
        pk.y = cvtpk(acc[mf][nf][2], acc[mf][nf][3]);
        *(uint2*)(smem + c * 264 + r0v) = pk;
      }
    __syncthreads();
    #pragma unroll
    for (int p = 0; p < 8; p++){
      const int cid = p * 512 + tid;
      const int c = cid >> 5, bb = (cid >> 1) & 15, sh = cid & 1;
      short8 st;
      #pragma unroll
      for (int j = 0; j < 8; j++) st[j] = (short)smem[c * 264 + (sh * 8 + j) * 16 + bb];
      const int oo = o0 + c;
      const int bh = bb * 16 + (oo >> 6), d = oo & 63;
      *(short8*)(vT + ((size_t)bh * 64 + d) * 512 + mt * 16 + sh * 8) = st;
    }
  } else {
    #pragma unroll
    for (int h2 = 0; h2 < 2; h2++){
      __syncthreads();
      if ((wm >> 1) == h2){
        #pragma unroll
        for (int mf = 0; mf < 4; mf++)
          #pragma unroll
          for (int nf = 0; nf < 4; nf++)
            #pragma unroll
            for (int rg = 0; rg < 4; rg++)
              smem[((wm & 1) * 64 + mf * 16 + lq * 4 + rg) * 136 + wn * 64 + nf * 16 + lr]
                  = f2bf(acc[mf][nf][rg]);
      }
      __syncthreads();
      if (which == 3){
        #pragma unroll
        for (int p = 0; p < 4; p++){
          const int cid = p * 512 + tid;
          const int lrow = cid >> 4, cg = cid & 15;
          short8 vv = *(const short8*)(smem + lrow * 136 + cg * 8);
          *(short8*)(rbb + (size_t)(m0 + h2 * 128 + lrow) * 1024 + o0 + cg * 8) = vv;
        }
      } else {
        unsigned short* dst = (which == 0) ? qb : kb;
        #pragma unroll
        for (int p = 0; p < 4; p++){
          const int cid = p * 512 + tid;
          const int lrow = cid >> 4, cg = cid & 15;
          short8 vv = *(const short8*)(smem + lrow * 136 + cg * 8);
          const int rowi = m0 + h2 * 128 + lrow;
          const int s = rowi >> 4, bb = rowi & 15;
          const int oo = o0 + cg * 8;
          const int bh = bb * 16 + (oo >> 6), d = oo & 63;
          *(short8*)(dst + ((size_t)bh * 512 + s) * 64 + d) = vv;
        }
      }
    }
  }
  #undef STAGE_H
  #undef PHASE
}

// ---------------- fused attention (swapped QK^T) ----------------
// 32 q-rows/block, 4 waves, 4096 blocks; bf16 out.
// Phase A computes MFMA(K,Q) so each lane holds 4 consecutive k-scores of ONE
// q-row (q=lr): e1 writes are b64, z1 is lane-local + 2 shuffles.
// Phase B: e2 pass only. Phase C unchanged.
__global__ __launch_bounds__(256, 4) void attn_kernel(
    const unsigned short* __restrict__ qg, const unsigned short* __restrict__ kg,
    const unsigned short* __restrict__ vt,
    const unsigned char* __restrict__ mbits, const unsigned char* __restrict__ wbits,
    unsigned short* __restrict__ outp)
{
  __shared__ __align__(16) unsigned short sE[32 * 520];
  __shared__ float zbuf1[128];    // [row][wave]
  __shared__ float sfin[32];
  const int bid = ((blockIdx.x & 7) << 9) | (blockIdx.x >> 3);  // XCD swizzle
  const int qt = bid & 15, h = (bid >> 4) & 15, b = bid >> 8;   // qt-fastest: K/V L2 reuse
  const int tid = threadIdx.x, w = tid >> 6, l = tid & 63;
  const int lr = l & 15, lq = l >> 4;
  const int bh = b * 16 + h;
  const unsigned short* qp = qg + ((size_t)bh * 512 + qt * 32) * 64;
  const unsigned short* kp = kg + (size_t)bh * 512 * 64;
  const unsigned short* vp = vt + (size_t)bh * 64 * 512;

  const unsigned char* mbase = mbits + ((size_t)(b * 512 + qt * 32)) * 64;
  const unsigned char* wrb   = wbits + ((size_t)(b * 512 + qt * 32)) * 64;

  // masks for this lane's q-rows (t*16+lr), this wave's 128 cols; pre-shift by
  // lq*4 so bit (kf_local*16 + rg) selects col w*128+kf*16+lq*4+rg.
  unsigned long long mus[2][2];
  #pragma unroll
  for (int t = 0; t < 2; t++){
    const unsigned char* rp = mbase + (size_t)(t * 16 + lr) * 64 + w * 16;
    mus[t][0] = (*(const unsigned long long*)(rp    )) >> (lq * 4);
    mus[t][1] = (*(const unsigned long long*)(rp + 8)) >> (lq * 4);
  }

  // ---- Phase A: swapped QK^T, masked e1 -> LDS (b64), lane-local z1 ----
  short8 qa[2][2];
  #pragma unroll
  for (int t = 0; t < 2; t++){
    qa[t][0] = *(const short8*)(qp + (t * 16 + lr) * 64 + lq * 8);
    qa[t][1] = *(const short8*)(qp + (t * 16 + lr) * 64 + 32 + lq * 8);
  }
  const float CEXP = 0.18033688011112042f;   // 0.125 * log2(e)
  float z1p[2] = {0.f, 0.f};
  #pragma unroll
  for (int kf = 0; kf < 8; kf++){
    const unsigned short* kr = kp + (size_t)(w * 128 + kf * 16 + lr) * 64;
    short8 k0 = *(const short8*)(kr + lq * 8);
    short8 k1 = *(const short8*)(kr + 32 + lq * 8);
    // swapped: A = K frag (row=k-col), B = Q frag (col=q-row)
    f32x4 a0 = {}, a1 = {};
    a0 = MFMA_BF16(k0, qa[0][0], a0);
    a1 = MFMA_BF16(k0, qa[1][0], a1);
    a0 = MFMA_BF16(k1, qa[0][1], a0);
    a1 = MFMA_BF16(k1, qa[1][1], a1);
    // lane holds S[q = t*16+lr][k = w*128 + kf*16 + lq*4 + rg]
    #pragma unroll
    for (int t = 0; t < 2; t++){
      f32x4 a = t ? a1 : a0;
      float v[4];
      #pragma unroll
      for (int rg = 0; rg < 4; rg++){
        float e = __builtin_amdgcn_exp2f(a[rg] * CEXP);
        const unsigned int bit = (unsigned int)(
            (kf < 4 ? mus[t][0] >> (kf * 16 + rg)
                    : mus[t][1] >> ((kf - 4) * 16 + rg))) & 1u;
        v[rg] = bit ? e : 0.f;
        z1p[t] += v[rg];
      }
      uint2 pk;
      pk.x = cvtpk(v[0], v[1]);
      pk.y = cvtpk(v[2], v[3]);
      *(uint2*)(sE + (t * 16 + lr) * 520 + w * 128 + kf * 16 + lq * 4) = pk;
    }
  }
  // row-sum: lanes sharing lr hold disjoint k-subsets -> xor 16, 32
  #pragma unroll
  for (int t = 0; t < 2; t++){
    z1p[t] += __shfl_xor(z1p[t], 16, 64);
    z1p[t] += __shfl_xor(z1p[t], 32, 64);
  }
  if (lq == 0){
    zbuf1[(lr) * 4 + w] = z1p[0];
    zbuf1[(16 + lr) * 4 + w] = z1p[1];
  }

  // Phase-B wmask bytes (rows g*16 + w*4 + rr), loads overlap the barrier
  unsigned int wby[2][4];
  #pragma unroll
  for (int g = 0; g < 2; g++)
    #pragma unroll
    for (int rr = 0; rr < 4; rr++)
      wby[g][rr] = wrb[(g * 16 + w * 4 + rr) * 64 + l];
  __syncthreads();

  // ---- Phase B: second softmax only (z1 known), 2 groups x 4 rows ----
  #pragma unroll
  for (int g = 0; g < 2; g++){
    const int row0 = g * 16 + w * 4;
    uint4 ev[4];
    float i1L[4];
    #pragma unroll
    for (int rr = 0; rr < 4; rr++){
      ev[rr] = *(const uint4*)(sE + (row0 + rr) * 520 + l * 8);
      float4 zz = *(const float4*)&zbuf1[(row0 + rr) * 4];
      i1L[rr] = 1.4426950408889634f / (zz.x + zz.y + zz.z + zz.w);
    }
    float e2[4][8]; float z2[4];
    #pragma unroll
    for (int rr = 0; rr < 4; rr++){
      float e1m[8];
      unpack8(ev[rr], e1m);
      const unsigned int wv = wby[g][rr];
      float z = 0.f;
      #pragma unroll
      for (int j = 0; j < 8; j++){
        float t = __builtin_amdgcn_exp2f(e1m[j] * i1L[rr]);
        e2[rr][j] = ((wv >> j) & 1u) ? t : 0.f;
        z += e2[rr][j];
      }
      z2[rr] = z;
    }
    #pragma unroll
    for (int mm = 32; mm; mm >>= 1){
      #pragma unroll
      for (int rr = 0; rr < 4; rr++) z2[rr] += __shfl_xor(z2[rr], mm, 64);
    }
    #pragma unroll
    for (int rr = 0; rr < 4; rr++){
      uint4 oo;
      oo.x = cvtpk(e2[rr][0], e2[rr][1]); oo.y = cvtpk(e2[rr][2], e2[rr][3]);
      oo.z = cvtpk(e2[rr][4], e2[rr][5]); oo.w = cvtpk(e2[rr][6], e2[rr][7]);
      *(uint4*)(sE + (row0 + rr) * 520 + l * 8) = oo;
      if (l == 0) sfin[row0 + rr] = 1.f / (z2[rr] + 1e-10f);
    }
  }
  __syncthreads();

  // ---- Phase C: 2 po chains sharing each V frag; d-frag [16w,16w+16) ----
  {
    f32x4 po0 = {}, po1 = {};
    #pragma unroll
    for (int ks = 0; ks < 16; ks++){
      short8 vf = *(const short8*)(vp + (size_t)(w * 16 + lr) * 512 + ks * 32 + lq * 8);
      short8 af0 = *(const short8*)(sE + (     lr) * 520 + ks * 32 + lq * 8);
      short8 af1 = *(const short8*)(sE + (16 + lr) * 520 + ks * 32 + lq * 8);
      po0 = MFMA_BF16(af0, vf, po0);
      po1 = MFMA_BF16(af1, vf, po1);
    }
    #pragma unroll
    for (int rg = 0; rg < 4; rg++){
      const int r0 = lq * 4 + rg;
      outp[((size_t)(qt * 32 + r0) * 16 + b) * 1024 + h * 64 + w * 16 + lr]
          = f2bf(po0[rg] * sfin[r0]);
      outp[((size_t)(qt * 32 + 16 + r0) * 16 + b) * 1024 + h * 64 + w * 16 + lr]
          = f2bf(po1[rg] * sfin[16 + r0]);
    }
  }
}

// ---------------- gate + mix ----------------
__global__ __launch_bounds__(256) void gate_kernel(
    const unsigned short* __restrict__ outp, const unsigned short* __restrict__ rbb,
    const float* __restrict__ wba, const float* __restrict__ wbb,
    float* __restrict__ y)
{
  const int t = blockIdx.x * 4 + (threadIdx.x >> 6);
  const int l = threadIdx.x & 63;
  const unsigned short* o = outp + (size_t)t * 1024;
  const unsigned short* r = rbb + (size_t)t * 1024;
  float ov[16], rv[16];
  float acc = 0.f;
  #pragma unroll
  for (int j = 0; j < 16; j++){
    const int e = j * 64 + l;
    ov[j] = __uint_as_float((unsigned int)o[e] << 16);
    rv[j] = __uint_as_float((unsigned int)r[e] << 16);
    acc += ov[j] * wba[e] + rv[j] * wbb[e];
  }
  const float dot = wred_sum(acc);
  const float g = 1.f / (1.f + __builtin_amdgcn_exp2f(-dot * 1.4426950408889634f));
  float* yo = y + (size_t)t * 1024;
  #pragma unroll
  for (int j = 0; j < 16; j++){
    const int e = j * 64 + l;
    yo[e] = g * rv[j] + (1.f - g) * ov[j];
  }
}

// ---------------- launch ----------------
extern "C" void kernel_launch(void* const* d_in, const int* in_sizes, int n_in,
                              void* d_out, int out_size, void* d_ws, size_t ws_size,
                              hipStream_t stream)
{
  (void)in_sizes; (void)n_in; (void)out_size; (void)ws_size;
  const float* x   = (const float*)d_in[0];
  const int* mask  = (const int*)d_in[1];
  const int* wmask = (const int*)d_in[2];
  const float* Wq  = (const float*)d_in[3];
  const float* Wk  = (const float*)d_in[4];
  const float* Wv  = (const float*)d_in[5];
  const float* Ws  = (const float*)d_in[6];
  const float* Wb  = (const float*)d_in[7];

  char* ws = (char*)d_ws;
  unsigned short* xbf = (unsigned short*)ws; ws += 16777216;
  unsigned short* bm  = (unsigned short*)ws; ws += 8388608;
  unsigned short* qb  = (unsigned short*)ws; ws += 16777216;
  unsigned short* kb  = (unsigned short*)ws; ws += 16777216;
  unsigned short* vT  = (unsigned short*)ws; ws += 16777216;
  unsigned short* rbb = (unsigned short*)ws; ws += 16777216;
  unsigned short* op  = (unsigned short*)ws; ws += 16777216;
  float* wba = (float*)ws; ws += 4096;
  float* wbb = (float*)ws; ws += 4096;
  unsigned long long* mb64 = (unsigned long long*)xbf;
  unsigned long long* wb64 = (unsigned long long*)bm;

  cvt_x_kernel<<<8192, 256, 0, stream>>>(x, xbf);
  cvt_w_kernel<<<4096, 256, 0, stream>>>(Wq, Wk, Wv, Ws, bm);
  wb_prep_kernel<<<4, 256, 0, stream>>>(Wb, wba, wbb);
  gemm_proj_kernel<<<1024, 512, 0, stream>>>(xbf, bm, qb, kb, vT, rbb);
  mask_prep_kernel<<<16384, 256, 0, stream>>>(mask, wmask, mb64, wb64);
  attn_kernel<<<4096, 256, 0, stream>>>(qb, kb, vT,
      (const unsigned char*)mb64, (const unsigned char*)wb64, op);
  gate_kernel<<<2048, 256, 0, stream>>>(op, rbb, wba, wbb, (float*)d_out);
}

// Round 15
// 176.007 us; speedup vs baseline: 1.0992x; 1.0165x over previous
//
#include <hip/hip_runtime.h>
#include <hip/hip_bf16.h>
#include <stdint.h>

typedef __attribute__((ext_vector_type(8))) short short8;
typedef __attribute__((ext_vector_type(4))) float f32x4;
typedef __attribute__((ext_vector_type(4))) unsigned short ushort4v;

#define MFMA_BF16(a,b,c) __builtin_amdgcn_mfma_f32_16x16x32_bf16((a),(b),(c),0,0,0)

static __device__ __forceinline__ unsigned short f2bf(float f){
  union { float fv; unsigned int u; } c; c.fv = f;
  unsigned int u = c.u;
  return (unsigned short)((u + 0x7fffu + ((u >> 16) & 1u)) >> 16);
}

static __device__ __forceinline__ unsigned int cvtpk(float a, float b){
  unsigned int r;
  asm("v_cvt_pk_bf16_f32 %0, %1, %2" : "=v"(r) : "v"(a), "v"(b));
  return r;
}

static __device__ __forceinline__ void gload_lds16(const void* g, void* l){
  __builtin_amdgcn_global_load_lds(
      (const __attribute__((address_space(1))) void*)g,
      (__attribute__((address_space(3))) void*)l, 16, 0, 0);
}

static __device__ __forceinline__ float wred_sum(float v){
  #pragma unroll
  for (int m = 32; m; m >>= 1) v += __shfl_xor(v, m, 64);
  return v;
}

static __device__ __forceinline__ void unpack8(uint4 u, float* f){
  f[0] = __uint_as_float(u.x << 16); f[1] = __uint_as_float(u.x & 0xFFFF0000u);
  f[2] = __uint_as_float(u.y << 16); f[3] = __uint_as_float(u.y & 0xFFFF0000u);
  f[4] = __uint_as_float(u.z << 16); f[5] = __uint_as_float(u.z & 0xFFFF0000u);
  f[6] = __uint_as_float(u.w << 16); f[7] = __uint_as_float(u.w & 0xFFFF0000u);
}

// ---------------- fused prep kernel: cvt_x | cvt_w | wb | mask bits ----------------
__global__ __launch_bounds__(256) void prep_kernel(
    const float* __restrict__ x,
    const float* __restrict__ Wq, const float* __restrict__ Wk,
    const float* __restrict__ Wv, const float* __restrict__ Ws,
    const float* __restrict__ Wb,
    const int* __restrict__ m, const int* __restrict__ wm,
    unsigned short* __restrict__ xbf, unsigned short* __restrict__ bmat,
    float* __restrict__ wba, float* __restrict__ wbb,
    unsigned long long* __restrict__ mb, unsigned long long* __restrict__ wb)
{
  const int bid = blockIdx.x;
  const int tid = threadIdx.x;
  if (bid < 8192){
    // cvt_x: 2,097,152 float4s
    const int i = bid * 256 + tid;
    float4 f = ((const float4*)x)[i];
    ushort4v r;
    r[0] = f2bf(f.x); r[1] = f2bf(f.y); r[2] = f2bf(f.z); r[3] = f2bf(f.w);
    ((ushort4v*)xbf)[i] = r;
  } else if (bid < 12288){
    // cvt_w: 1,048,576 float4s across 4 matrices
    const int i = (bid - 8192) * 256 + tid;
    const int which = i >> 18;
    const float* src = (which == 0) ? Wq : (which == 1) ? Wk : (which == 2) ? Wv : Ws;
    float4 f = ((const float4*)src)[i & 262143];
    ushort4v r;
    r[0] = f2bf(f.x); r[1] = f2bf(f.y); r[2] = f2bf(f.z); r[3] = f2bf(f.w);
    ((ushort4v*)bmat)[i] = r;
  } else if (bid < 12292){
    // wb fold: 1024 elems
    const int e = (bid - 12288) * 256 + tid;
    wba[e] = Wb[e]        + Wb[2048 + e];
    wbb[e] = Wb[1024 + e] - Wb[2048 + e];
  } else {
    // mask bit-planes via ballot: 4,194,304 elems each
    const size_t i = (size_t)(bid - 12292) * 256 + tid;
    const int a = m[i];
    const int c = wm[i];
    unsigned long long ba = __ballot(a != 0);
    unsigned long long bc = __ballot(c != 0);
    if ((tid & 63) == 0){
      mb[i >> 6] = ba;
      wb[i >> 6] = bc;
    }
  }
}

// ---------------- fused projection GEMM (pipelined, phase-split) ----------------
__global__ __launch_bounds__(512, 1) void gemm_proj_kernel(
    const unsigned short* __restrict__ X, const unsigned short* __restrict__ B,
    unsigned short* __restrict__ qb, unsigned short* __restrict__ kb,
    unsigned short* __restrict__ vT, unsigned short* __restrict__ rbb)
{
  __shared__ __align__(16) unsigned short smem[73728];   // 3 x 48KB tiles
  const int tid = threadIdx.x;
  const int w = tid >> 6, l = tid & 63;
  const int lr = l & 15, lq = l >> 4;
  const int wm = w >> 1, wn = w & 1;
  const int xcd = blockIdx.x & 7, o = blockIdx.x >> 3;           // o in [0,128)
  const int mt = xcd * 4 + (o & 3), nt = o >> 2;                 // mt-fastest in XCD
  const int m0 = mt * 256, n0 = nt * 128;
  const int lrow8 = l >> 3, lc = l & 7;

  f32x4 acc[4][4] = {};

  #define STAGE_H(T, H) { \
    const int bufo_ = ((T) % 3) * 24576; \
    const int kk_ = (T) * 64; \
    _Pragma("unroll") \
    for (int j = (H) * 2; j < (H) * 2 + 2; j++){ \
      const int seg = w + j * 8; \
      const int r = seg * 8 + lrow8; \
      gload_lds16(X + (size_t)(m0 + r) * 1024 + kk_ + ((lc ^ (r & 7)) * 8), \
                  smem + bufo_ + seg * 512); \
    } \
    { \
      const int seg = w + (H) * 8; \
      const int r = seg * 8 + lrow8; \
      gload_lds16(B + (size_t)(n0 + r) * 1024 + kk_ + ((lc ^ (r & 7)) * 8), \
                  smem + bufo_ + 16384 + seg * 512); \
    } }

  #define PHASE(T, SUBK, DOSTAGE) { \
    const int bo_ = ((T) % 3) * 24576; \
    short8 av[4], bv[4]; \
    const int pc = ((((SUBK) * 4 + lq) ^ (lr & 7)) * 8); \
    _Pragma("unroll") \
    for (int mf = 0; mf < 4; mf++) \
      av[mf] = *(const short8*)(smem + bo_ + (wm * 64 + mf * 16 + lr) * 64 + pc); \
    _Pragma("unroll") \
    for (int nf = 0; nf < 4; nf++) \
      bv[nf] = *(const short8*)(smem + bo_ + 16384 + (wn * 64 + nf * 16 + lr) * 64 + pc); \
    if (DOSTAGE) STAGE_H((T) + 2, SUBK) \
    asm volatile("s_waitcnt lgkmcnt(0)" ::: "memory"); \
    __builtin_amdgcn_sched_barrier(0); \
    __builtin_amdgcn_s_setprio(1); \
    _Pragma("unroll") \
    for (int mf = 0; mf < 4; mf++) \
      _Pragma("unroll") \
      for (int nf = 0; nf < 4; nf++) \
        acc[mf][nf] = MFMA_BF16(av[mf], bv[nf], acc[mf][nf]); \
    __builtin_amdgcn_s_setprio(0); }

  STAGE_H(0, 0) STAGE_H(0, 1)
  STAGE_H(1, 0) STAGE_H(1, 1)

  for (int t = 0; t < 15; t++){
    asm volatile("s_waitcnt vmcnt(6)" ::: "memory");
    __builtin_amdgcn_s_barrier();
    const bool st = (t < 14);
    PHASE(t, 0, st)
    __builtin_amdgcn_s_barrier();
    PHASE(t, 1, st)
  }
  asm volatile("s_waitcnt vmcnt(0)" ::: "memory");
  __builtin_amdgcn_s_barrier();
  PHASE(15, 0, false)
  PHASE(15, 1, false)

  // ---- epilogue: LDS-staged coalesced stores ----
  const int which = nt >> 3;
  const int o0 = (nt & 7) * 128;
  if (which == 2){
    __syncthreads();
    #pragma unroll
    for (int mf = 0; mf < 4; mf++)
      #pragma unroll
      for (int nf = 0; nf < 4; nf++){
        const int c = wn * 64 + nf * 16 + lr;
        const int r0v = wm * 64 + mf * 16 + lq * 4;
        uint2 pk;
        pk.x = cvtpk(acc[mf][nf][0], acc[mf][nf][1]);
        pk.y = cvtpk(acc[mf][nf][2], acc[mf][nf][3]);
        *(uint2*)(smem + c * 264 + r0v) = pk;
      }
    __syncthreads();
    #pragma unroll
    for (int p = 0; p < 8; p++){
      const int cid = p * 512 + tid;
      const int c = cid >> 5, bb = (cid >> 1) & 15, sh = cid & 1;
      short8 st;
      #pragma unroll
      for (int j = 0; j < 8; j++) st[j] = (short)smem[c * 264 + (sh * 8 + j) * 16 + bb];
      const int oo = o0 + c;
      const int bh = bb * 16 + (oo >> 6), d = oo & 63;
      *(short8*)(vT + ((size_t)bh * 64 + d) * 512 + mt * 16 + sh * 8) = st;
    }
  } else {
    #pragma unroll
    for (int h2 = 0; h2 < 2; h2++){
      __syncthreads();
      if ((wm >> 1) == h2){
        #pragma unroll
        for (int mf = 0; mf < 4; mf++)
          #pragma unroll
          for (int nf = 0; nf < 4; nf++)
            #pragma unroll
            for (int rg = 0; rg < 4; rg++)
              smem[((wm & 1) * 64 + mf * 16 + lq * 4 + rg) * 136 + wn * 64 + nf * 16 + lr]
                  = f2bf(acc[mf][nf][rg]);
      }
      __syncthreads();
      if (which == 3){
        #pragma unroll
        for (int p = 0; p < 4; p++){
          const int cid = p * 512 + tid;
          const int lrow = cid >> 4, cg = cid & 15;
          short8 vv = *(const short8*)(smem + lrow * 136 + cg * 8);
          *(short8*)(rbb + (size_t)(m0 + h2 * 128 + lrow) * 1024 + o0 + cg * 8) = vv;
        }
      } else {
        unsigned short* dst = (which == 0) ? qb : kb;
        #pragma unroll
        for (int p = 0; p < 4; p++){
          const int cid = p * 512 + tid;
          const int lrow = cid >> 4, cg = cid & 15;
          short8 vv = *(const short8*)(smem + lrow * 136 + cg * 8);
          const int rowi = m0 + h2 * 128 + lrow;
          const int s = rowi >> 4, bb = rowi & 15;
          const int oo = o0 + cg * 8;
          const int bh = bb * 16 + (oo >> 6), d = oo & 63;
          *(short8*)(dst + ((size_t)bh * 512 + s) * 64 + d) = vv;
        }
      }
    }
  }
  #undef STAGE_H
  #undef PHASE
}

// ---------------- fused attention (swapped QK^T) ----------------
__global__ __launch_bounds__(256, 4) void attn_kernel(
    const unsigned short* __restrict__ qg, const unsigned short* __restrict__ kg,
    const unsigned short* __restrict__ vt,
    const unsigned char* __restrict__ mbits, const unsigned char* __restrict__ wbits,
    unsigned short* __restrict__ outp)
{
  __shared__ __align__(16) unsigned short sE[32 * 520];
  __shared__ float zbuf1[128];    // [row][wave]
  __shared__ float sfin[32];
  const int bid = ((blockIdx.x & 7) << 9) | (blockIdx.x >> 3);  // XCD swizzle
  const int qt = bid & 15, h = (bid >> 4) & 15, b = bid >> 8;   // qt-fastest: K/V L2 reuse
  const int tid = threadIdx.x, w = tid >> 6, l = tid & 63;
  const int lr = l & 15, lq = l >> 4;
  const int bh = b * 16 + h;
  const unsigned short* qp = qg + ((size_t)bh * 512 + qt * 32) * 64;
  const unsigned short* kp = kg + (size_t)bh * 512 * 64;
  const unsigned short* vp = vt + (size_t)bh * 64 * 512;

  const unsigned char* mbase = mbits + ((size_t)(b * 512 + qt * 32)) * 64;
  const unsigned char* wrb   = wbits + ((size_t)(b * 512 + qt * 32)) * 64;

  unsigned long long mus[2][2];
  #pragma unroll
  for (int t = 0; t < 2; t++){
    const unsigned char* rp = mbase + (size_t)(t * 16 + lr) * 64 + w * 16;
    mus[t][0] = (*(const unsigned long long*)(rp    )) >> (lq * 4);
    mus[t][1] = (*(const unsigned long long*)(rp + 8)) >> (lq * 4);
  }

  // ---- Phase A: swapped QK^T, masked e1 -> LDS (b64), lane-local z1 ----
  short8 qa[2][2];
  #pragma unroll
  for (int t = 0; t < 2; t++){
    qa[t][0] = *(const short8*)(qp + (t * 16 + lr) * 64 + lq * 8);
    qa[t][1] = *(const short8*)(qp + (t * 16 + lr) * 64 + 32 + lq * 8);
  }
  const float CEXP = 0.18033688011112042f;   // 0.125 * log2(e)
  float z1p[2] = {0.f, 0.f};
  #pragma unroll
  for (int kf = 0; kf < 8; kf++){
    const unsigned short* kr = kp + (size_t)(w * 128 + kf * 16 + lr) * 64;
    short8 k0 = *(const short8*)(kr + lq * 8);
    short8 k1 = *(const short8*)(kr + 32 + lq * 8);
    f32x4 a0 = {}, a1 = {};
    a0 = MFMA_BF16(k0, qa[0][0], a0);
    a1 = MFMA_BF16(k0, qa[1][0], a1);
    a0 = MFMA_BF16(k1, qa[0][1], a0);
    a1 = MFMA_BF16(k1, qa[1][1], a1);
    #pragma unroll
    for (int t = 0; t < 2; t++){
      f32x4 a = t ? a1 : a0;
      float v[4];
      #pragma unroll
      for (int rg = 0; rg < 4; rg++){
        float e = __builtin_amdgcn_exp2f(a[rg] * CEXP);
        const unsigned int bit = (unsigned int)(
            (kf < 4 ? mus[t][0] >> (kf * 16 + rg)
                    : mus[t][1] >> ((kf - 4) * 16 + rg))) & 1u;
        v[rg] = bit ? e : 0.f;
        z1p[t] += v[rg];
      }
      uint2 pk;
      pk.x = cvtpk(v[0], v[1]);
      pk.y = cvtpk(v[2], v[3]);
      *(uint2*)(sE + (t * 16 + lr) * 520 + w * 128 + kf * 16 + lq * 4) = pk;
    }
  }
  #pragma unroll
  for (int t = 0; t < 2; t++){
    z1p[t] += __shfl_xor(z1p[t], 16, 64);
    z1p[t] += __shfl_xor(z1p[t], 32, 64);
  }
  if (lq == 0){
    zbuf1[(lr) * 4 + w] = z1p[0];
    zbuf1[(16 + lr) * 4 + w] = z1p[1];
  }

  unsigned int wby[2][4];
  #pragma unroll
  for (int g = 0; g < 2; g++)
    #pragma unroll
    for (int rr = 0; rr < 4; rr++)
      wby[g][rr] = wrb[(g * 16 + w * 4 + rr) * 64 + l];
  __syncthreads();

  // ---- Phase B: second softmax only (z1 known), 2 groups x 4 rows ----
  #pragma unroll
  for (int g = 0; g < 2; g++){
    const int row0 = g * 16 + w * 4;
    uint4 ev[4];
    float i1L[4];
    #pragma unroll
    for (int rr = 0; rr < 4; rr++){
      ev[rr] = *(const uint4*)(sE + (row0 + rr) * 520 + l * 8);
      float4 zz = *(const float4*)&zbuf1[(row0 + rr) * 4];
      i1L[rr] = 1.4426950408889634f / (zz.x + zz.y + zz.z + zz.w);
    }
    float e2[4][8]; float z2[4];
    #pragma unroll
    for (int rr = 0; rr < 4; rr++){
      float e1m[8];
      unpack8(ev[rr], e1m);
      const unsigned int wv = wby[g][rr];
      float z = 0.f;
      #pragma unroll
      for (int j = 0; j < 8; j++){
        float t = __builtin_amdgcn_exp2f(e1m[j] * i1L[rr]);
        e2[rr][j] = ((wv >> j) & 1u) ? t : 0.f;
        z += e2[rr][j];
      }
      z2[rr] = z;
    }
    #pragma unroll
    for (int mm = 32; mm; mm >>= 1){
      #pragma unroll
      for (int rr = 0; rr < 4; rr++) z2[rr] += __shfl_xor(z2[rr], mm, 64);
    }
    #pragma unroll
    for (int rr = 0; rr < 4; rr++){
      uint4 oo;
      oo.x = cvtpk(e2[rr][0], e2[rr][1]); oo.y = cvtpk(e2[rr][2], e2[rr][3]);
      oo.z = cvtpk(e2[rr][4], e2[rr][5]); oo.w = cvtpk(e2[rr][6], e2[rr][7]);
      *(uint4*)(sE + (row0 + rr) * 520 + l * 8) = oo;
      if (l == 0) sfin[row0 + rr] = 1.f / (z2[rr] + 1e-10f);
    }
  }
  __syncthreads();

  // ---- Phase C: 2 po chains sharing each V frag; d-frag [16w,16w+16) ----
  {
    f32x4 po0 = {}, po1 = {};
    #pragma unroll
    for (int ks = 0; ks < 16; ks++){
      short8 vf = *(const short8*)(vp + (size_t)(w * 16 + lr) * 512 + ks * 32 + lq * 8);
      short8 af0 = *(const short8*)(sE + (     lr) * 520 + ks * 32 + lq * 8);
      short8 af1 = *(const short8*)(sE + (16 + lr) * 520 + ks * 32 + lq * 8);
      po0 = MFMA_BF16(af0, vf, po0);
      po1 = MFMA_BF16(af1, vf, po1);
    }
    #pragma unroll
    for (int rg = 0; rg < 4; rg++){
      const int r0 = lq * 4 + rg;
      outp[((size_t)(qt * 32 + r0) * 16 + b) * 1024 + h * 64 + w * 16 + lr]
          = f2bf(po0[rg] * sfin[r0]);
      outp[((size_t)(qt * 32 + 16 + r0) * 16 + b) * 1024 + h * 64 + w * 16 + lr]
          = f2bf(po1[rg] * sfin[16 + r0]);
    }
  }
}

// ---------------- gate + mix (vectorized: wave per token) ----------------
__global__ __launch_bounds__(256) void gate_kernel(
    const unsigned short* __restrict__ outp, const unsigned short* __restrict__ rbb,
    const float* __restrict__ wba, const float* __restrict__ wbb,
    float* __restrict__ y)
{
  const int t = blockIdx.x * 4 + (threadIdx.x >> 6);
  const int l = threadIdx.x & 63;
  const unsigned short* o = outp + (size_t)t * 1024;
  const unsigned short* r = rbb + (size_t)t * 1024;
  float ov[16], rv[16];
  float acc = 0.f;
  #pragma unroll
  for (int hh = 0; hh < 2; hh++){
    const int e0 = hh * 512 + l * 8;
    short8 ox = *(const short8*)(o + e0);
    short8 rx = *(const short8*)(r + e0);
    float4 wa0 = *(const float4*)(wba + e0);
    float4 wa1 = *(const float4*)(wba + e0 + 4);
    float4 wb0 = *(const float4*)(wbb + e0);
    float4 wb1 = *(const float4*)(wbb + e0 + 4);
    const float wav[8] = {wa0.x, wa0.y, wa0.z, wa0.w, wa1.x, wa1.y, wa1.z, wa1.w};
    const float wbv[8] = {wb0.x, wb0.y, wb0.z, wb0.w, wb1.x, wb1.y, wb1.z, wb1.w};
    #pragma unroll
    for (int j = 0; j < 8; j++){
      float ovj = __uint_as_float((unsigned int)(unsigned short)ox[j] << 16);
      float rvj = __uint_as_float((unsigned int)(unsigned short)rx[j] << 16);
      ov[hh * 8 + j] = ovj;
      rv[hh * 8 + j] = rvj;
      acc += ovj * wav[j] + rvj * wbv[j];
    }
  }
  const float dot = wred_sum(acc);
  const float g = 1.f / (1.f + __builtin_amdgcn_exp2f(-dot * 1.4426950408889634f));
  float* yo = y + (size_t)t * 1024;
  #pragma unroll
  for (int hh = 0; hh < 2; hh++){
    const int e0 = hh * 512 + l * 8;
    float4 o1, o2;
    o1.x = g * rv[hh*8+0] + (1.f - g) * ov[hh*8+0];
    o1.y = g * rv[hh*8+1] + (1.f - g) * ov[hh*8+1];
    o1.z = g * rv[hh*8+2] + (1.f - g) * ov[hh*8+2];
    o1.w = g * rv[hh*8+3] + (1.f - g) * ov[hh*8+3];
    o2.x = g * rv[hh*8+4] + (1.f - g) * ov[hh*8+4];
    o2.y = g * rv[hh*8+5] + (1.f - g) * ov[hh*8+5];
    o2.z = g * rv[hh*8+6] + (1.f - g) * ov[hh*8+6];
    o2.w = g * rv[hh*8+7] + (1.f - g) * ov[hh*8+7];
    *(float4*)(yo + e0) = o1;
    *(float4*)(yo + e0 + 4) = o2;
  }
}

// ---------------- launch ----------------
extern "C" void kernel_launch(void* const* d_in, const int* in_sizes, int n_in,
                              void* d_out, int out_size, void* d_ws, size_t ws_size,
                              hipStream_t stream)
{
  (void)in_sizes; (void)n_in; (void)out_size; (void)ws_size;
  const float* x   = (const float*)d_in[0];
  const int* mask  = (const int*)d_in[1];
  const int* wmask = (const int*)d_in[2];
  const float* Wq  = (const float*)d_in[3];
  const float* Wk  = (const float*)d_in[4];
  const float* Wv  = (const float*)d_in[5];
  const float* Ws  = (const float*)d_in[6];
  const float* Wb  = (const float*)d_in[7];

  char* ws = (char*)d_ws;
  unsigned short* xbf = (unsigned short*)ws; ws += 16777216;
  unsigned short* bm  = (unsigned short*)ws; ws += 8388608;
  unsigned short* qb  = (unsigned short*)ws; ws += 16777216;
  unsigned short* kb  = (unsigned short*)ws; ws += 16777216;
  unsigned short* vT  = (unsigned short*)ws; ws += 16777216;
  unsigned short* rbb = (unsigned short*)ws; ws += 16777216;
  unsigned short* op  = (unsigned short*)ws; ws += 16777216;
  float* wba = (float*)ws; ws += 4096;
  float* wbb = (float*)ws; ws += 4096;
  unsigned long long* mb64 = (unsigned long long*)ws; ws += 524288;
  unsigned long long* wb64 = (unsigned long long*)ws; ws += 524288;

  prep_kernel<<<28676, 256, 0, stream>>>(x, Wq, Wk, Wv, Ws, Wb, mask, wmask,
                                         xbf, bm, wba, wbb, mb64, wb64);
  gemm_proj_kernel<<<1024, 512, 0, stream>>>(xbf, bm, qb, kb, vT, rbb);
  attn_kernel<<<4096, 256, 0, stream>>>(qb, kb, vT,
      (const unsigned char*)mb64, (const unsigned char*)wb64, op);
  gate_kernel<<<2048, 256, 0, stream>>>(op, rbb, wba, wbb, (float*)d_out);
}

// Round 16
// 175.364 us; speedup vs baseline: 1.1032x; 1.0037x over previous
//
#include <hip/hip_runtime.h>
#include <hip/hip_bf16.h>
#include <stdint.h>

typedef __attribute__((ext_vector_type(8))) short short8;
typedef __attribute__((ext_vector_type(4))) float f32x4;
typedef __attribute__((ext_vector_type(4))) unsigned short ushort4v;

#define MFMA_BF16(a,b,c) __builtin_amdgcn_mfma_f32_16x16x32_bf16((a),(b),(c),0,0,0)

static __device__ __forceinline__ unsigned short f2bf(float f){
  union { float fv; unsigned int u; } c; c.fv = f;
  unsigned int u = c.u;
  return (unsigned short)((u + 0x7fffu + ((u >> 16) & 1u)) >> 16);
}

static __device__ __forceinline__ unsigned int cvtpk(float a, float b){
  unsigned int r;
  asm("v_cvt_pk_bf16_f32 %0, %1, %2" : "=v"(r) : "v"(a), "v"(b));
  return r;
}

static __device__ __forceinline__ void gload_lds16(const void* g, void* l){
  __builtin_amdgcn_global_load_lds(
      (const __attribute__((address_space(1))) void*)g,
      (__attribute__((address_space(3))) void*)l, 16, 0, 0);
}

static __device__ __forceinline__ float wred_sum(float v){
  #pragma unroll
  for (int m = 32; m; m >>= 1) v += __shfl_xor(v, m, 64);
  return v;
}

static __device__ __forceinline__ void unpack8(uint4 u, float* f){
  f[0] = __uint_as_float(u.x << 16); f[1] = __uint_as_float(u.x & 0xFFFF0000u);
  f[2] = __uint_as_float(u.y << 16); f[3] = __uint_as_float(u.y & 0xFFFF0000u);
  f[4] = __uint_as_float(u.z << 16); f[5] = __uint_as_float(u.z & 0xFFFF0000u);
  f[6] = __uint_as_float(u.w << 16); f[7] = __uint_as_float(u.w & 0xFFFF0000u);
}

// ---------------- fused prep kernel: cvt_x | cvt_w | wb | mask bits ----------------
__global__ __launch_bounds__(256) void prep_kernel(
    const float* __restrict__ x,
    const float* __restrict__ Wq, const float* __restrict__ Wk,
    const float* __restrict__ Wv, const float* __restrict__ Ws,
    const float* __restrict__ Wb,
    const int* __restrict__ m, const int* __restrict__ wm,
    unsigned short* __restrict__ xbf, unsigned short* __restrict__ bmat,
    float* __restrict__ wba, float* __restrict__ wbb,
    unsigned long long* __restrict__ mb, unsigned long long* __restrict__ wb)
{
  const int bid = blockIdx.x;
  const int tid = threadIdx.x;
  if (bid < 8192){
    const int i = bid * 256 + tid;
    float4 f = ((const float4*)x)[i];
    ushort4v r;
    r[0] = f2bf(f.x); r[1] = f2bf(f.y); r[2] = f2bf(f.z); r[3] = f2bf(f.w);
    ((ushort4v*)xbf)[i] = r;
  } else if (bid < 12288){
    const int i = (bid - 8192) * 256 + tid;
    const int which = i >> 18;
    const float* src = (which == 0) ? Wq : (which == 1) ? Wk : (which == 2) ? Wv : Ws;
    float4 f = ((const float4*)src)[i & 262143];
    ushort4v r;
    r[0] = f2bf(f.x); r[1] = f2bf(f.y); r[2] = f2bf(f.z); r[3] = f2bf(f.w);
    ((ushort4v*)bmat)[i] = r;
  } else if (bid < 12292){
    const int e = (bid - 12288) * 256 + tid;
    wba[e] = Wb[e]        + Wb[2048 + e];
    wbb[e] = Wb[1024 + e] - Wb[2048 + e];
  } else {
    const size_t i = (size_t)(bid - 12292) * 256 + tid;
    const int a = m[i];
    const int c = wm[i];
    unsigned long long ba = __ballot(a != 0);
    unsigned long long bc = __ballot(c != 0);
    if ((tid & 63) == 0){
      mb[i >> 6] = ba;
      wb[i >> 6] = bc;
    }
  }
}

// ---------------- fused projection GEMM (pipelined, phase-split) ----------------
__global__ __launch_bounds__(512, 1) void gemm_proj_kernel(
    const unsigned short* __restrict__ X, const unsigned short* __restrict__ B,
    unsigned short* __restrict__ qb, unsigned short* __restrict__ kb,
    unsigned short* __restrict__ vT, unsigned short* __restrict__ rbb)
{
  __shared__ __align__(16) unsigned short smem[73728];   // 3 x 24KB tiles
  const int tid = threadIdx.x;
  const int w = tid >> 6, l = tid & 63;
  const int lr = l & 15, lq = l >> 4;
  const int wm = w >> 1, wn = w & 1;
  const int xcd = blockIdx.x & 7, o = blockIdx.x >> 3;           // o in [0,128)
  const int mt = xcd * 4 + (o & 3), nt = o >> 2;                 // mt-fastest in XCD
  const int m0 = mt * 256, n0 = nt * 128;
  const int lrow8 = l >> 3, lc = l & 7;

  f32x4 acc[4][4] = {};

  #define STAGE_H(T, H) { \
    const int bufo_ = ((T) % 3) * 24576; \
    const int kk_ = (T) * 64; \
    _Pragma("unroll") \
    for (int j = (H) * 2; j < (H) * 2 + 2; j++){ \
      const int seg = w + j * 8; \
      const int r = seg * 8 + lrow8; \
      gload_lds16(X + (size_t)(m0 + r) * 1024 + kk_ + ((lc ^ (r & 7)) * 8), \
                  smem + bufo_ + seg * 512); \
    } \
    { \
      const int seg = w + (H) * 8; \
      const int r = seg * 8 + lrow8; \
      gload_lds16(B + (size_t)(n0 + r) * 1024 + kk_ + ((lc ^ (r & 7)) * 8), \
                  smem + bufo_ + 16384 + seg * 512); \
    } }

  #define PHASE(T, SUBK, DOSTAGE) { \
    const int bo_ = ((T) % 3) * 24576; \
    short8 av[4], bv[4]; \
    const int pc = ((((SUBK) * 4 + lq) ^ (lr & 7)) * 8); \
    _Pragma("unroll") \
    for (int mf = 0; mf < 4; mf++) \
      av[mf] = *(const short8*)(smem + bo_ + (wm * 64 + mf * 16 + lr) * 64 + pc); \
    _Pragma("unroll") \
    for (int nf = 0; nf < 4; nf++) \
      bv[nf] = *(const short8*)(smem + bo_ + 16384 + (wn * 64 + nf * 16 + lr) * 64 + pc); \
    if (DOSTAGE) STAGE_H((T) + 2, SUBK) \
    asm volatile("s_waitcnt lgkmcnt(0)" ::: "memory"); \
    __builtin_amdgcn_sched_barrier(0); \
    __builtin_amdgcn_s_setprio(1); \
    _Pragma("unroll") \
    for (int mf = 0; mf < 4; mf++) \
      _Pragma("unroll") \
      for (int nf = 0; nf < 4; nf++) \
        acc[mf][nf] = MFMA_BF16(av[mf], bv[nf], acc[mf][nf]); \
    __builtin_amdgcn_s_setprio(0); }

  STAGE_H(0, 0) STAGE_H(0, 1)
  STAGE_H(1, 0) STAGE_H(1, 1)

  for (int t = 0; t < 15; t++){
    asm volatile("s_waitcnt vmcnt(6)" ::: "memory");
    __builtin_amdgcn_s_barrier();
    const bool st = (t < 14);
    PHASE(t, 0, st)
    __builtin_amdgcn_s_barrier();
    PHASE(t, 1, st)
  }
  asm volatile("s_waitcnt vmcnt(0)" ::: "memory");
  __builtin_amdgcn_s_barrier();
  PHASE(15, 0, false)
  PHASE(15, 1, false)

  // ---- epilogue: LDS-staged coalesced stores ----
  const int which = nt >> 3;
  const int o0 = (nt & 7) * 128;
  if (which == 2){
    __syncthreads();
    #pragma unroll
    for (int mf = 0; mf < 4; mf++)
      #pragma unroll
      for (int nf = 0; nf < 4; nf++){
        const int c = wn * 64 + nf * 16 + lr;
        const int r0v = wm * 64 + mf * 16 + lq * 4;
        uint2 pk;
        pk.x = cvtpk(acc[mf][nf][0], acc[mf][nf][1]);
        pk.y = cvtpk(acc[mf][nf][2], acc[mf][nf][3]);
        *(uint2*)(smem + c * 264 + r0v) = pk;
      }
    __syncthreads();
    #pragma unroll
    for (int p = 0; p < 8; p++){
      const int cid = p * 512 + tid;
      const int c = cid >> 5, bb = (cid >> 1) & 15, sh = cid & 1;
      short8 st;
      #pragma unroll
      for (int j = 0; j < 8; j++) st[j] = (short)smem[c * 264 + (sh * 8 + j) * 16 + bb];
      const int oo = o0 + c;
      const int bh = bb * 16 + (oo >> 6), d = oo & 63;
      *(short8*)(vT + ((size_t)bh * 64 + d) * 512 + mt * 16 + sh * 8) = st;
    }
  } else {
    #pragma unroll
    for (int h2 = 0; h2 < 2; h2++){
      __syncthreads();
      if ((wm >> 1) == h2){
        #pragma unroll
        for (int mf = 0; mf < 4; mf++)
          #pragma unroll
          for (int nf = 0; nf < 4; nf++)
            #pragma unroll
            for (int rg = 0; rg < 4; rg++)
              smem[((wm & 1) * 64 + mf * 16 + lq * 4 + rg) * 136 + wn * 64 + nf * 16 + lr]
                  = f2bf(acc[mf][nf][rg]);
      }
      __syncthreads();
      if (which == 3){
        #pragma unroll
        for (int p = 0; p < 4; p++){
          const int cid = p * 512 + tid;
          const int lrow = cid >> 4, cg = cid & 15;
          short8 vv = *(const short8*)(smem + lrow * 136 + cg * 8);
          *(short8*)(rbb + (size_t)(m0 + h2 * 128 + lrow) * 1024 + o0 + cg * 8) = vv;
        }
      } else {
        unsigned short* dst = (which == 0) ? qb : kb;
        #pragma unroll
        for (int p = 0; p < 4; p++){
          const int cid = p * 512 + tid;
          const int lrow = cid >> 4, cg = cid & 15;
          short8 vv = *(const short8*)(smem + lrow * 136 + cg * 8);
          const int rowi = m0 + h2 * 128 + lrow;
          const int s = rowi >> 4, bb = rowi & 15;
          const int oo = o0 + cg * 8;
          const int bh = bb * 16 + (oo >> 6), d = oo & 63;
          *(short8*)(dst + ((size_t)bh * 512 + s) * 64 + d) = vv;
        }
      }
    }
  }
  #undef STAGE_H
  #undef PHASE
}

// ---------------- fused attention (swapped QK^T, pipelined PV) ----------------
// 32 q-rows/block, 4 waves, 4096 blocks; bf16 out. LDS caps 4 blocks/CU, which
// permits up to 128 VGPRs at 4 waves/SIMD -> launch_bounds(256,2) frees the
// allocator to pipeline K/V loads (was capped at 64 VGPR -> serialized loads).
__global__ __launch_bounds__(256, 2) void attn_kernel(
    const unsigned short* __restrict__ qg, const unsigned short* __restrict__ kg,
    const unsigned short* __restrict__ vt,
    const unsigned char* __restrict__ mbits, const unsigned char* __restrict__ wbits,
    unsigned short* __restrict__ outp)
{
  __shared__ __align__(16) unsigned short sE[32 * 520];
  __shared__ float zbuf1[128];    // [row][wave]
  __shared__ float sfin[32];
  const int bid = ((blockIdx.x & 7) << 9) | (blockIdx.x >> 3);  // XCD swizzle
  const int qt = bid & 15, h = (bid >> 4) & 15, b = bid >> 8;   // qt-fastest: K/V L2 reuse
  const int tid = threadIdx.x, w = tid >> 6, l = tid & 63;
  const int lr = l & 15, lq = l >> 4;
  const int bh = b * 16 + h;
  const unsigned short* qp = qg + ((size_t)bh * 512 + qt * 32) * 64;
  const unsigned short* kp = kg + (size_t)bh * 512 * 64;
  const unsigned short* vp = vt + (size_t)bh * 64 * 512;

  const unsigned char* mbase = mbits + ((size_t)(b * 512 + qt * 32)) * 64;
  const unsigned char* wrb   = wbits + ((size_t)(b * 512 + qt * 32)) * 64;

  unsigned long long mus[2][2];
  #pragma unroll
  for (int t = 0; t < 2; t++){
    const unsigned char* rp = mbase + (size_t)(t * 16 + lr) * 64 + w * 16;
    mus[t][0] = (*(const unsigned long long*)(rp    )) >> (lq * 4);
    mus[t][1] = (*(const unsigned long long*)(rp + 8)) >> (lq * 4);
  }

  // ---- Phase A: swapped QK^T, masked e1 -> LDS (b64), lane-local z1 ----
  short8 qa[2][2];
  #pragma unroll
  for (int t = 0; t < 2; t++){
    qa[t][0] = *(const short8*)(qp + (t * 16 + lr) * 64 + lq * 8);
    qa[t][1] = *(const short8*)(qp + (t * 16 + lr) * 64 + 32 + lq * 8);
  }
  const float CEXP = 0.18033688011112042f;   // 0.125 * log2(e)
  float z1p[2] = {0.f, 0.f};
  #pragma unroll
  for (int kf = 0; kf < 8; kf++){
    const unsigned short* kr = kp + (size_t)(w * 128 + kf * 16 + lr) * 64;
    short8 k0 = *(const short8*)(kr + lq * 8);
    short8 k1 = *(const short8*)(kr + 32 + lq * 8);
    f32x4 a0 = {}, a1 = {};
    a0 = MFMA_BF16(k0, qa[0][0], a0);
    a1 = MFMA_BF16(k0, qa[1][0], a1);
    a0 = MFMA_BF16(k1, qa[0][1], a0);
    a1 = MFMA_BF16(k1, qa[1][1], a1);
    #pragma unroll
    for (int t = 0; t < 2; t++){
      f32x4 a = t ? a1 : a0;
      float v[4];
      #pragma unroll
      for (int rg = 0; rg < 4; rg++){
        float e = __builtin_amdgcn_exp2f(a[rg] * CEXP);
        const unsigned int bit = (unsigned int)(
            (kf < 4 ? mus[t][0] >> (kf * 16 + rg)
                    : mus[t][1] >> ((kf - 4) * 16 + rg))) & 1u;
        v[rg] = bit ? e : 0.f;
        z1p[t] += v[rg];
      }
      uint2 pk;
      pk.x = cvtpk(v[0], v[1]);
      pk.y = cvtpk(v[2], v[3]);
      *(uint2*)(sE + (t * 16 + lr) * 520 + w * 128 + kf * 16 + lq * 4) = pk;
    }
  }
  #pragma unroll
  for (int t = 0; t < 2; t++){
    z1p[t] += __shfl_xor(z1p[t], 16, 64);
    z1p[t] += __shfl_xor(z1p[t], 32, 64);
  }
  if (lq == 0){
    zbuf1[(lr) * 4 + w] = z1p[0];
    zbuf1[(16 + lr) * 4 + w] = z1p[1];
  }

  unsigned int wby[2][4];
  #pragma unroll
  for (int g = 0; g < 2; g++)
    #pragma unroll
    for (int rr = 0; rr < 4; rr++)
      wby[g][rr] = wrb[(g * 16 + w * 4 + rr) * 64 + l];
  __syncthreads();

  // ---- Phase B: second softmax only (z1 known), 2 groups x 4 rows ----
  #pragma unroll
  for (int g = 0; g < 2; g++){
    const int row0 = g * 16 + w * 4;
    uint4 ev[4];
    float i1L[4];
    #pragma unroll
    for (int rr = 0; rr < 4; rr++){
      ev[rr] = *(const uint4*)(sE + (row0 + rr) * 520 + l * 8);
      float4 zz = *(const float4*)&zbuf1[(row0 + rr) * 4];
      i1L[rr] = 1.4426950408889634f / (zz.x + zz.y + zz.z + zz.w);
    }
    float e2[4][8]; float z2[4];
    #pragma unroll
    for (int rr = 0; rr < 4; rr++){
      float e1m[8];
      unpack8(ev[rr], e1m);
      const unsigned int wv = wby[g][rr];
      float z = 0.f;
      #pragma unroll
      for (int j = 0; j < 8; j++){
        float t = __builtin_amdgcn_exp2f(e1m[j] * i1L[rr]);
        e2[rr][j] = ((wv >> j) & 1u) ? t : 0.f;
        z += e2[rr][j];
      }
      z2[rr] = z;
    }
    #pragma unroll
    for (int mm = 32; mm; mm >>= 1){
      #pragma unroll
      for (int rr = 0; rr < 4; rr++) z2[rr] += __shfl_xor(z2[rr], mm, 64);
    }
    #pragma unroll
    for (int rr = 0; rr < 4; rr++){
      uint4 oo;
      oo.x = cvtpk(e2[rr][0], e2[rr][1]); oo.y = cvtpk(e2[rr][2], e2[rr][3]);
      oo.z = cvtpk(e2[rr][4], e2[rr][5]); oo.w = cvtpk(e2[rr][6], e2[rr][7]);
      *(uint4*)(sE + (row0 + rr) * 520 + l * 8) = oo;
      if (l == 0) sfin[row0 + rr] = 1.f / (z2[rr] + 1e-10f);
    }
  }
  __syncthreads();

  // ---- Phase C: PV with 4-deep V prefetch; d-frag [16w,16w+16) ----
  {
    f32x4 po0 = {}, po1 = {};
    const unsigned short* vrow = vp + (size_t)(w * 16 + lr) * 512 + lq * 8;
    short8 vv0 = *(const short8*)(vrow);
    short8 vv1 = *(const short8*)(vrow + 32);
    short8 vv2 = *(const short8*)(vrow + 64);
    short8 vv3 = *(const short8*)(vrow + 96);
    #pragma unroll
    for (int ks4 = 0; ks4 < 4; ks4++){
      short8 cur0 = vv0, cur1 = vv1, cur2 = vv2, cur3 = vv3;
      if (ks4 < 3){
        vv0 = *(const short8*)(vrow + (ks4 * 4 + 4) * 32);
        vv1 = *(const short8*)(vrow + (ks4 * 4 + 5) * 32);
        vv2 = *(const short8*)(vrow + (ks4 * 4 + 6) * 32);
        vv3 = *(const short8*)(vrow + (ks4 * 4 + 7) * 32);
      }
      #pragma unroll
      for (int j = 0; j < 4; j++){
        const int ks = ks4 * 4 + j;
        short8 cv = (j == 0) ? cur0 : (j == 1) ? cur1 : (j == 2) ? cur2 : cur3;
        short8 af0 = *(const short8*)(sE + (     lr) * 520 + ks * 32 + lq * 8);
        short8 af1 = *(const short8*)(sE + (16 + lr) * 520 + ks * 32 + lq * 8);
        po0 = MFMA_BF16(af0, cv, po0);
        po1 = MFMA_BF16(af1, cv, po1);
      }
    }
    #pragma unroll
    for (int rg = 0; rg < 4; rg++){
      const int r0 = lq * 4 + rg;
      outp[((size_t)(qt * 32 + r0) * 16 + b) * 1024 + h * 64 + w * 16 + lr]
          = f2bf(po0[rg] * sfin[r0]);
      outp[((size_t)(qt * 32 + 16 + r0) * 16 + b) * 1024 + h * 64 + w * 16 + lr]
          = f2bf(po1[rg] * sfin[16 + r0]);
    }
  }
}

// ---------------- gate + mix (vectorized: wave per token) ----------------
__global__ __launch_bounds__(256) void gate_kernel(
    const unsigned short* __restrict__ outp, const unsigned short* __restrict__ rbb,
    const float* __restrict__ wba, const float* __restrict__ wbb,
    float* __restrict__ y)
{
  const int t = blockIdx.x * 4 + (threadIdx.x >> 6);
  const int l = threadIdx.x & 63;
  const unsigned short* o = outp + (size_t)t * 1024;
  const unsigned short* r = rbb + (size_t)t * 1024;
  float ov[16], rv[16];
  float acc = 0.f;
  #pragma unroll
  for (int hh = 0; hh < 2; hh++){
    const int e0 = hh * 512 + l * 8;
    short8 ox = *(const short8*)(o + e0);
    short8 rx = *(const short8*)(r + e0);
    float4 wa0 = *(const float4*)(wba + e0);
    float4 wa1 = *(const float4*)(wba + e0 + 4);
    float4 wb0 = *(const float4*)(wbb + e0);
    float4 wb1 = *(const float4*)(wbb + e0 + 4);
    const float wav[8] = {wa0.x, wa0.y, wa0.z, wa0.w, wa1.x, wa1.y, wa1.z, wa1.w};
    const float wbv[8] = {wb0.x, wb0.y, wb0.z, wb0.w, wb1.x, wb1.y, wb1.z, wb1.w};
    #pragma unroll
    for (int j = 0; j < 8; j++){
      float ovj = __uint_as_float((unsigned int)(unsigned short)ox[j] << 16);
      float rvj = __uint_as_float((unsigned int)(unsigned short)rx[j] << 16);
      ov[hh * 8 + j] = ovj;
      rv[hh * 8 + j] = rvj;
      acc += ovj * wav[j] + rvj * wbv[j];
    }
  }
  const float dot = wred_sum(acc);
  const float g = 1.f / (1.f + __builtin_amdgcn_exp2f(-dot * 1.4426950408889634f));
  float* yo = y + (size_t)t * 1024;
  #pragma unroll
  for (int hh = 0; hh < 2; hh++){
    const int e0 = hh * 512 + l * 8;
    float4 o1, o2;
    o1.x = g * rv[hh*8+0] + (1.f - g) * ov[hh*8+0];
    o1.y = g * rv[hh*8+1] + (1.f - g) * ov[hh*8+1];
    o1.z = g * rv[hh*8+2] + (1.f - g) * ov[hh*8+2];
    o1.w = g * rv[hh*8+3] + (1.f - g) * ov[hh*8+3];
    o2.x = g * rv[hh*8+4] + (1.f - g) * ov[hh*8+4];
    o2.y = g * rv[hh*8+5] + (1.f - g) * ov[hh*8+5];
    o2.z = g * rv[hh*8+6] + (1.f - g) * ov[hh*8+6];
    o2.w = g * rv[hh*8+7] + (1.f - g) * ov[hh*8+7];
    *(float4*)(yo + e0) = o1;
    *(float4*)(yo + e0 + 4) = o2;
  }
}

// ---------------- launch ----------------
extern "C" void kernel_launch(void* const* d_in, const int* in_sizes, int n_in,
                              void* d_out, int out_size, void* d_ws, size_t ws_size,
                              hipStream_t stream)
{
  (void)in_sizes; (void)n_in; (void)out_size; (void)ws_size;
  const float* x   = (const float*)d_in[0];
  const int* mask  = (const int*)d_in[1];
  const int* wmask = (const int*)d_in[2];
  const float* Wq  = (const float*)d_in[3];
  const float* Wk  = (const float*)d_in[4];
  const float* Wv  = (const float*)d_in[5];
  const float* Ws  = (const float*)d_in[6];
  const float* Wb  = (const float*)d_in[7];

  char* ws = (char*)d_ws;
  unsigned short* xbf = (unsigned short*)ws; ws += 16777216;
  unsigned short* bm  = (unsigned short*)ws; ws += 8388608;
  unsigned short* qb  = (unsigned short*)ws; ws += 16777216;
  unsigned short* kb  = (unsigned short*)ws; ws += 16777216;
  unsigned short* vT  = (unsigned short*)ws; ws += 16777216;
  unsigned short* rbb = (unsigned short*)ws; ws += 16777216;
  unsigned short* op  = (unsigned short*)ws; ws += 16777216;
  float* wba = (float*)ws; ws += 4096;
  float* wbb = (float*)ws; ws += 4096;
  unsigned long long* mb64 = (unsigned long long*)ws; ws += 524288;
  unsigned long long* wb64 = (unsigned long long*)ws; ws += 524288;

  prep_kernel<<<28676, 256, 0, stream>>>(x, Wq, Wk, Wv, Ws, Wb, mask, wmask,
                                         xbf, bm, wba, wbb, mb64, wb64);
  gemm_proj_kernel<<<1024, 512, 0, stream>>>(xbf, bm, qb, kb, vT, rbb);
  attn_kernel<<<4096, 256, 0, stream>>>(qb, kb, vT,
      (const unsigned char*)mb64, (const unsigned char*)wb64, op);
  gate_kernel<<<2048, 256, 0, stream>>>(op, rbb, wba, wbb, (float*)d_out);
}